// Round 1
// baseline (969.193 us; speedup 1.0000x reference)
//
#include <hip/hip_runtime.h>
#include <math.h>

#define BB   32
#define CCH  128
#define NPIX 1024
#define HH   32
#define WWW  32
#define CRED 16

// ---------------------------------------------------------------------------
// Pointwise (1x1 conv) GEMM: out[b][o][p] = act-less( sum_c W1[o][c]*X1[b][c][p]
//                         (+ sum_c W2[o][c]*X2[b][c][p]) (+ bias[o]) (+ res) )
// Register-tiled f32: block=256, tile O x P, micro MO x 4.
// ---------------------------------------------------------------------------
template<int O, int P>
__global__ __launch_bounds__(256)
void pw_kernel(float* __restrict__ out,
               const float* __restrict__ X1,
               const float* __restrict__ W1, int ldw1,
               const float* __restrict__ X2,
               const float* __restrict__ W2, int ldw2,
               const float* __restrict__ bias,
               const float* __restrict__ res)
{
    constexpr int KC = 32;
    constexpr int PG = P / 4;             // pixel groups per row
    constexpr int MO = (O * P) / (256 * 4);
    static_assert(PG * 4 == P, "P%4");
    static_assert(MO * 256 * 4 == O * P, "tile");

    __shared__ float Xs[KC][P];
    __shared__ float Ws[KC][O + 1];       // +1 pad: conflict-free write/read

    const int tid = threadIdx.x;
    const int b   = blockIdx.y;
    const int p0  = blockIdx.x * P;
    const int po  = tid % PG;
    const int oo  = tid / PG;

    float acc[MO][4];
    #pragma unroll
    for (int i = 0; i < MO; ++i)
        #pragma unroll
        for (int j = 0; j < 4; ++j) acc[i][j] = 0.f;

    for (int pass = 0; pass < 2; ++pass) {
        const float* X  = pass ? X2 : X1;
        const float* W  = pass ? W2 : W1;
        const int   ldw = pass ? ldw2 : ldw1;
        if (!X) continue;                              // block-uniform
        const float* Xb = X + (size_t)b * CCH * NPIX;
        for (int k0 = 0; k0 < CCH; k0 += KC) {
            __syncthreads();
            // stage X chunk [KC][P] (float4, coalesced)
            for (int idx = tid; idx < KC * P / 4; idx += 256) {
                int r  = idx / (P / 4);
                int cp = (idx % (P / 4)) * 4;
                *(float4*)&Xs[r][cp] =
                    *(const float4*)&Xb[(size_t)(k0 + r) * NPIX + p0 + cp];
            }
            // stage W chunk transposed: Ws[kk][o] = W[o][k0+kk]
            for (int idx = tid; idx < O * KC; idx += 256) {
                int o  = idx / KC;
                int cc = idx % KC;
                Ws[cc][o] = W[(size_t)o * ldw + k0 + cc];
            }
            __syncthreads();
            #pragma unroll 4
            for (int kk = 0; kk < KC; ++kk) {
                float4 xv = *(float4*)&Xs[kk][po * 4];
                #pragma unroll
                for (int i = 0; i < MO; ++i) {
                    float wv = Ws[kk][oo * MO + i];
                    acc[i][0] += wv * xv.x;
                    acc[i][1] += wv * xv.y;
                    acc[i][2] += wv * xv.z;
                    acc[i][3] += wv * xv.w;
                }
            }
        }
    }

    #pragma unroll
    for (int i = 0; i < MO; ++i) {
        int o = oo * MO + i;
        float bv = bias ? bias[o] : 0.f;
        float4 r4 = make_float4(acc[i][0] + bv, acc[i][1] + bv,
                                acc[i][2] + bv, acc[i][3] + bv);
        size_t off = ((size_t)b * O + o) * NPIX + p0 + po * 4;
        if (res) {
            float4 rr = *(const float4*)&res[off];
            r4.x += rr.x; r4.y += rr.y; r4.z += rr.z; r4.w += rr.w;
        }
        *(float4*)&out[off] = r4;
    }
}

// ---------------------------------------------------------------------------
// Depthwise 3x3 SAME (correlation, matches XLA). grid (C, B, 2):
//  z==0: dst0 = dw(src0,k0);  z==1: dst1 = dw(src1,k1)
// ---------------------------------------------------------------------------
__global__ __launch_bounds__(256)
void dw_kernel(float* __restrict__ dst0, const float* __restrict__ src0,
               const float* __restrict__ k0w,
               float* __restrict__ dst1, const float* __restrict__ src1,
               const float* __restrict__ k1w)
{
    const int c = blockIdx.x, b = blockIdx.y;
    const float* src; const float* kw; float* dst;
    if (blockIdx.z == 0) { src = src0; kw = k0w; dst = dst0; }
    else                 { src = src1; kw = k1w; dst = dst1; }
    src += ((size_t)b * CCH + c) * NPIX;
    dst += ((size_t)b * CCH + c) * NPIX;

    float k[9];
    #pragma unroll
    for (int j = 0; j < 9; ++j) k[j] = kw[c * 9 + j];

    __shared__ float t[34][36];
    const int tid = threadIdx.x;
    for (int idx = tid; idx < 34 * 34; idx += 256) {
        int y = idx / 34, x = idx % 34;
        int gy = y - 1, gx = x - 1;
        t[y][x] = (gy >= 0 && gy < 32 && gx >= 0 && gx < 32)
                      ? src[gy * 32 + gx] : 0.f;
    }
    __syncthreads();
    const int x = tid % 32, y0 = tid / 32;
    #pragma unroll
    for (int q = 0; q < 4; ++q) {
        int y = y0 + 8 * q;
        float s = 0.f;
        #pragma unroll
        for (int dy = 0; dy < 3; ++dy)
            #pragma unroll
            for (int dx = 0; dx < 3; ++dx)
                s += t[y + dy][x + dx] * k[dy * 3 + dx];
        dst[y * 32 + x] = s;
    }
}

// ---------------------------------------------------------------------------
// Dual-stream attention. Shared Q [B][16][N]; per z: K [B][16][N], V [B][128][N],
// out Z[b][c][i] = sum_j V[c][j]*exp(S[i][j]) / sum_j exp(S[i][j]),
// S[i][j] = sum_k Q[k][i]K[k][j].  No max-subtraction (|S| <~ 15, safe in f32).
// Block: 256 thr, TI=64 query rows, TJ=32 key tile.
// ---------------------------------------------------------------------------
__global__ __launch_bounds__(256)
void attn_kernel(float* __restrict__ Zh, float* __restrict__ Zm,
                 const float* __restrict__ Qg,
                 const float* __restrict__ Khg, const float* __restrict__ Kmg,
                 const float* __restrict__ Vhg, const float* __restrict__ Vmg)
{
    const int b  = blockIdx.y;
    const int i0 = blockIdx.x * 64;
    const float* Kg; const float* Vg; float* Og;
    if (blockIdx.z == 0) { Kg = Khg; Vg = Vhg; Og = Zh; }
    else                 { Kg = Kmg; Vg = Vmg; Og = Zm; }

    __shared__ float Qs[CRED][65];
    __shared__ float Ks[CRED][33];
    __shared__ float Vs[32][132];
    __shared__ float Ps[64][66];
    __shared__ float linv_s[64];

    const int tid = threadIdx.x;
    for (int idx = tid; idx < CRED * 64; idx += 256) {
        int k = idx / 64, i = idx % 64;
        Qs[k][i] = Qg[((size_t)b * CRED + k) * NPIX + i0 + i];
    }

    const int si    = tid % 64;
    const int sjg   = tid / 64;          // 0..3
    const int cbase = tid % 32;
    const int i0r   = (tid / 32) * 8;    // 0..56

    float acc[4][8];
    #pragma unroll
    for (int a = 0; a < 4; ++a)
        #pragma unroll
        for (int q = 0; q < 8; ++q) acc[a][q] = 0.f;
    float l_acc = 0.f;

    for (int j0 = 0; j0 < NPIX; j0 += 32) {
        __syncthreads();
        for (int idx = tid; idx < CRED * 32; idx += 256) {
            int k = idx / 32, j = idx % 32;
            Ks[k][j] = Kg[((size_t)b * CRED + k) * NPIX + j0 + j];
        }
        for (int idx = tid; idx < CCH * 32; idx += 256) {
            int j = idx % 32, c = idx / 32;          // lanes: consecutive j -> coalesced
            Vs[j][c] = Vg[((size_t)b * CCH + c) * NPIX + j0 + j];
        }
        __syncthreads();
        // S tile + exp
        float sacc[8];
        #pragma unroll
        for (int jj = 0; jj < 8; ++jj) sacc[jj] = 0.f;
        #pragma unroll 4
        for (int k = 0; k < CRED; ++k) {
            float q = Qs[k][si];
            #pragma unroll
            for (int jj = 0; jj < 8; ++jj)
                sacc[jj] += q * Ks[k][sjg * 8 + jj];
        }
        #pragma unroll
        for (int jj = 0; jj < 8; ++jj) {
            float p = __expf(sacc[jj]);
            l_acc += p;
            Ps[si][sjg * 8 + jj] = p;
        }
        __syncthreads();
        // apply: acc[ic][ii] over 32 j's (2 at a time)
        for (int j = 0; j < 32; j += 2) {
            float2 p2[8];
            #pragma unroll
            for (int ii = 0; ii < 8; ++ii)
                p2[ii] = *(const float2*)&Ps[i0r + ii][j];
            #pragma unroll
            for (int ic = 0; ic < 4; ++ic) {
                float v0 = Vs[j][cbase + 32 * ic];
                float v1 = Vs[j + 1][cbase + 32 * ic];
                #pragma unroll
                for (int ii = 0; ii < 8; ++ii)
                    acc[ic][ii] += v0 * p2[ii].x + v1 * p2[ii].y;
            }
        }
    }

    __syncthreads();
    float* red = &Ks[0][0];              // reuse (>=256 floats)
    red[tid] = l_acc;
    __syncthreads();
    if (tid < 64)
        linv_s[tid] = 1.f / (red[tid] + red[tid + 64] + red[tid + 128] + red[tid + 192]);
    __syncthreads();

    // transpose via LDS (reuse Ps, stride 66) -> coalesced stores
    float* T = &Ps[0][0];
    for (int g = 0; g < 4; ++g) {
        #pragma unroll
        for (int ii = 0; ii < 8; ++ii)
            T[cbase * 66 + i0r + ii] = acc[g][ii] * linv_s[i0r + ii];
        __syncthreads();
        for (int idx = tid; idx < 32 * 64; idx += 256) {
            int i = idx % 64, c2 = idx / 64;
            Og[((size_t)b * CCH + g * 32 + c2) * NPIX + i0 + i] = T[c2 * 66 + i];
        }
        __syncthreads();
    }
}

// ---------------------------------------------------------------------------
// Gate fusion: i=sig(G1), g=tanh(G2), o=sig(G3); m_t=(1-i)m_prev+i*g; om=o*m_t
// ---------------------------------------------------------------------------
__device__ __forceinline__ float sigf(float x) { return 1.f / (1.f + __expf(-x)); }

__global__ __launch_bounds__(256)
void combine_kernel(float* __restrict__ m_out, float* __restrict__ om,
                    const float* __restrict__ G1, const float* __restrict__ G2,
                    const float* __restrict__ G3, const float* __restrict__ mp)
{
    size_t idx = ((size_t)blockIdx.x * 256 + threadIdx.x) * 4;
    float4 a4 = *(const float4*)&G1[idx];
    float4 g4 = *(const float4*)&G2[idx];
    float4 o4 = *(const float4*)&G3[idx];
    float4 m4 = *(const float4*)&mp[idx];
    float ia[4] = {a4.x, a4.y, a4.z, a4.w};
    float ga[4] = {g4.x, g4.y, g4.z, g4.w};
    float oa[4] = {o4.x, o4.y, o4.z, o4.w};
    float ma[4] = {m4.x, m4.y, m4.z, m4.w};
    float mo[4], om4[4];
    #pragma unroll
    for (int j = 0; j < 4; ++j) {
        float it = sigf(ia[j]);
        float gt = tanhf(ga[j]);
        float ot = sigf(oa[j]);
        float mt = (1.f - it) * ma[j] + it * gt;
        mo[j]  = mt;
        om4[j] = ot * mt;
    }
    *(float4*)&m_out[idx] = make_float4(mo[0], mo[1], mo[2], mo[3]);
    *(float4*)&om[idx]    = make_float4(om4[0], om4[1], om4[2], om4[3]);
}

// ---------------------------------------------------------------------------
extern "C" void kernel_launch(void* const* d_in, const int* in_sizes, int n_in,
                              void* d_out, int out_size, void* d_ws, size_t ws_size,
                              hipStream_t stream)
{
    (void)in_sizes; (void)n_in; (void)out_size; (void)ws_size;
    const float* h_t    = (const float*)d_in[0];
    const float* m_prev = (const float*)d_in[1];
    const float* wq_h   = (const float*)d_in[2];
    const float* wk_h   = (const float*)d_in[3];
    const float* wv_h   = (const float*)d_in[4];
    const float* wk_m   = (const float*)d_in[5];
    const float* wv_m   = (const float*)d_in[6];
    const float* wz_w   = (const float*)d_in[7];
    const float* wz_b   = (const float*)d_in[8];
    const float* wmi_dw = (const float*)d_in[9];
    const float* wmi_pw = (const float*)d_in[10];
    const float* whi_dw = (const float*)d_in[11];
    const float* whi_pw = (const float*)d_in[12];
    const float* bi     = (const float*)d_in[13];
    const float* wmg_dw = (const float*)d_in[14];
    const float* wmg_pw = (const float*)d_in[15];
    const float* whg_dw = (const float*)d_in[16];
    const float* whg_pw = (const float*)d_in[17];
    const float* bg     = (const float*)d_in[18];
    const float* wmo_dw = (const float*)d_in[19];
    const float* wmo_pw = (const float*)d_in[20];
    const float* who_dw = (const float*)d_in[21];
    const float* who_pw = (const float*)d_in[22];
    const float* bo     = (const float*)d_in[23];
    const float* wf_w   = (const float*)d_in[24];
    const float* wf_b   = (const float*)d_in[25];

    float* out = (float*)d_out;               // [h_out | m_t]
    float* ws  = (float*)d_ws;

    const size_t SQ = (size_t)BB * CRED * NPIX;   // 524288
    const size_t SV = (size_t)BB * CCH * NPIX;    // 4194304
    float* Q  = ws;
    float* Kh = Q  + SQ;
    float* Km = Kh + SQ;
    float* Av = Km + SQ;   // Vh, later G1
    float* Bv = Av + SV;   // Vm, later G2
    float* Cv = Bv + SV;   // Zh, later G3
    float* Dv = Cv + SV;   // Zm, later OM
    float* Ev = Dv + SV;   // Z
    float* Fv = Ev + SV;   // dw(Z, .)
    float* Gv = Fv + SV;   // dw(h_t, .)

    dim3 blk(256);

    // Q / K / V projections
    pw_kernel<16, 128><<<dim3(NPIX / 128, BB), blk, 0, stream>>>(
        Q, h_t, wq_h, CCH, nullptr, nullptr, 0, nullptr, nullptr);
    pw_kernel<16, 128><<<dim3(NPIX / 128, BB), blk, 0, stream>>>(
        Kh, h_t, wk_h, CCH, nullptr, nullptr, 0, nullptr, nullptr);
    pw_kernel<128, 64><<<dim3(NPIX / 64, BB), blk, 0, stream>>>(
        Av, h_t, wv_h, CCH, nullptr, nullptr, 0, nullptr, nullptr);
    pw_kernel<16, 128><<<dim3(NPIX / 128, BB), blk, 0, stream>>>(
        Km, m_prev, wk_m, CCH, nullptr, nullptr, 0, nullptr, nullptr);
    pw_kernel<128, 64><<<dim3(NPIX / 64, BB), blk, 0, stream>>>(
        Bv, m_prev, wv_m, CCH, nullptr, nullptr, 0, nullptr, nullptr);

    // dual attention -> Zh(Cv), Zm(Dv)
    attn_kernel<<<dim3(NPIX / 64, BB, 2), blk, 0, stream>>>(
        Cv, Dv, Q, Kh, Km, Av, Bv);

    // Z = wz * [Zh; Zm] + wz_b   -> Ev
    pw_kernel<128, 64><<<dim3(NPIX / 64, BB), blk, 0, stream>>>(
        Ev, Cv, wz_w, 2 * CCH, Dv, wz_w + CCH, 2 * CCH, wz_b, nullptr);

    // gates: i -> Av, g -> Bv, o -> Cv
    dw_kernel<<<dim3(CCH, BB, 2), blk, 0, stream>>>(Fv, Ev, wmi_dw, Gv, h_t, whi_dw);
    pw_kernel<128, 64><<<dim3(NPIX / 64, BB), blk, 0, stream>>>(
        Av, Fv, wmi_pw, CCH, Gv, whi_pw, CCH, bi, nullptr);
    dw_kernel<<<dim3(CCH, BB, 2), blk, 0, stream>>>(Fv, Ev, wmg_dw, Gv, h_t, whg_dw);
    pw_kernel<128, 64><<<dim3(NPIX / 64, BB), blk, 0, stream>>>(
        Bv, Fv, wmg_pw, CCH, Gv, whg_pw, CCH, bg, nullptr);
    dw_kernel<<<dim3(CCH, BB, 2), blk, 0, stream>>>(Fv, Ev, wmo_dw, Gv, h_t, who_dw);
    pw_kernel<128, 64><<<dim3(NPIX / 64, BB), blk, 0, stream>>>(
        Cv, Fv, wmo_pw, CCH, Gv, who_pw, CCH, bo, nullptr);

    // m_t -> out+SV ; om -> Dv
    combine_kernel<<<dim3(SV / 1024), blk, 0, stream>>>(
        out + SV, Dv, Av, Bv, Cv, m_prev);

    // h_out = wf * om + wf_b + h_t  -> out
    pw_kernel<128, 64><<<dim3(NPIX / 64, BB), blk, 0, stream>>>(
        out, Dv, wf_w, CCH, nullptr, nullptr, 0, wf_b, h_t);
}

// Round 2
// 493.903 us; speedup vs baseline: 1.9623x; 1.9623x over previous
//
#include <hip/hip_runtime.h>
#include <hip/hip_bf16.h>
#include <math.h>

#define BB   32
#define CCH  128
#define NPIX 1024
#define CRED 16

typedef __attribute__((ext_vector_type(8)))  short short8;
typedef __attribute__((ext_vector_type(16))) float f32x16;

union Frag8 { short8 s8; unsigned u[4]; };

__device__ __forceinline__ unsigned pack2bf(float lo, float hi) {
    union { __hip_bfloat16 h; unsigned short u; } a, b;
    a.h = __float2bfloat16(lo);
    b.h = __float2bfloat16(hi);
    return (unsigned)a.u | ((unsigned)b.u << 16);
}

// ---------------------------------------------------------------------------
// Pointwise (1x1 conv) GEMM, f32 compute; optional bf16 output.
// out[b][o][p] = sum_c W1[o][c]X1[b][c][p] (+W2·X2) (+bias) (+res)
// ---------------------------------------------------------------------------
template<int O, int P, bool BF16OUT>
__global__ __launch_bounds__(256)
void pw_kernel(void* __restrict__ outv,
               const float* __restrict__ X1,
               const float* __restrict__ W1, int ldw1,
               const float* __restrict__ X2,
               const float* __restrict__ W2, int ldw2,
               const float* __restrict__ bias,
               const float* __restrict__ res)
{
    constexpr int KC = 32;
    constexpr int PG = P / 4;
    constexpr int MO = (O * P) / (256 * 4);
    static_assert(PG * 4 == P, "P%4");
    static_assert(MO * 256 * 4 == O * P, "tile");

    __shared__ float Xs[KC][P];
    __shared__ float Ws[KC][O + 1];

    const int tid = threadIdx.x;
    const int b   = blockIdx.y;
    const int p0  = blockIdx.x * P;
    const int po  = tid % PG;
    const int oo  = tid / PG;

    float acc[MO][4];
    #pragma unroll
    for (int i = 0; i < MO; ++i)
        #pragma unroll
        for (int j = 0; j < 4; ++j) acc[i][j] = 0.f;

    for (int pass = 0; pass < 2; ++pass) {
        const float* X  = pass ? X2 : X1;
        const float* W  = pass ? W2 : W1;
        const int   ldw = pass ? ldw2 : ldw1;
        if (!X) continue;
        const float* Xb = X + (size_t)b * CCH * NPIX;
        for (int k0 = 0; k0 < CCH; k0 += KC) {
            __syncthreads();
            for (int idx = tid; idx < KC * P / 4; idx += 256) {
                int r  = idx / (P / 4);
                int cp = (idx % (P / 4)) * 4;
                *(float4*)&Xs[r][cp] =
                    *(const float4*)&Xb[(size_t)(k0 + r) * NPIX + p0 + cp];
            }
            for (int idx = tid; idx < O * KC; idx += 256) {
                int o  = idx / KC;
                int cc = idx % KC;
                Ws[cc][o] = W[(size_t)o * ldw + k0 + cc];
            }
            __syncthreads();
            #pragma unroll 4
            for (int kk = 0; kk < KC; ++kk) {
                float4 xv = *(float4*)&Xs[kk][po * 4];
                #pragma unroll
                for (int i = 0; i < MO; ++i) {
                    float wv = Ws[kk][oo * MO + i];
                    acc[i][0] += wv * xv.x;
                    acc[i][1] += wv * xv.y;
                    acc[i][2] += wv * xv.z;
                    acc[i][3] += wv * xv.w;
                }
            }
        }
    }

    #pragma unroll
    for (int i = 0; i < MO; ++i) {
        int o = oo * MO + i;
        float bv = bias ? bias[o] : 0.f;
        float4 r4 = make_float4(acc[i][0] + bv, acc[i][1] + bv,
                                acc[i][2] + bv, acc[i][3] + bv);
        size_t off = ((size_t)b * O + o) * NPIX + p0 + po * 4;
        if (res) {
            float4 rr = *(const float4*)&res[off];
            r4.x += rr.x; r4.y += rr.y; r4.z += rr.z; r4.w += rr.w;
        }
        if (BF16OUT) {
            unsigned lo = pack2bf(r4.x, r4.y);
            unsigned hi = pack2bf(r4.z, r4.w);
            uint2 st = make_uint2(lo, hi);
            *(uint2*)((__hip_bfloat16*)outv + off) = st;
        } else {
            *(float4*)((float*)outv + off) = r4;
        }
    }
}

// ---------------------------------------------------------------------------
// Q/K projection -> transposed bf16 [B][NPIX][16]. z: 0=Q(h), 1=Kh(h), 2=Km(m)
// ---------------------------------------------------------------------------
__global__ __launch_bounds__(256)
void qkproj_kernel(__hip_bfloat16* __restrict__ Qt,
                   __hip_bfloat16* __restrict__ Kht,
                   __hip_bfloat16* __restrict__ Kmt,
                   const float* __restrict__ h_t,
                   const float* __restrict__ m_prev,
                   const float* __restrict__ wq,
                   const float* __restrict__ wkh,
                   const float* __restrict__ wkm)
{
    const int b  = blockIdx.y;
    const int p0 = blockIdx.x * 128;
    const float* X; const float* W; __hip_bfloat16* Out;
    if (blockIdx.z == 0)      { X = h_t;    W = wq;  Out = Qt;  }
    else if (blockIdx.z == 1) { X = h_t;    W = wkh; Out = Kht; }
    else                      { X = m_prev; W = wkm; Out = Kmt; }

    __shared__ float Ws[16][128];
    __shared__ float Xs[32][132];
    const int tid = threadIdx.x;
    for (int i = tid; i < 16 * 128; i += 256)
        Ws[i / 128][i % 128] = W[i];

    const float* Xb = X + (size_t)b * CCH * NPIX;
    const int pl = tid & 127;
    const int h8 = tid >> 7;       // wave-uniform

    float acc[8];
    #pragma unroll
    for (int e = 0; e < 8; ++e) acc[e] = 0.f;

    for (int c0 = 0; c0 < CCH; c0 += 32) {
        __syncthreads();
        for (int idx = tid; idx < 32 * 32; idx += 256) {
            int r = idx >> 5, cp = (idx & 31) << 2;
            *(float4*)&Xs[r][cp] =
                *(const float4*)&Xb[(size_t)(c0 + r) * NPIX + p0 + cp];
        }
        __syncthreads();
        #pragma unroll 8
        for (int cc = 0; cc < 32; ++cc) {
            float xv = Xs[cc][pl];
            #pragma unroll
            for (int e = 0; e < 8; ++e)
                acc[e] += Ws[h8 * 8 + e][c0 + cc] * xv;
        }
    }

    Frag8 f;
    #pragma unroll
    for (int w = 0; w < 4; ++w)
        f.u[w] = pack2bf(acc[2 * w], acc[2 * w + 1]);
    *(short8*)&Out[((size_t)b * NPIX + p0 + pl) * 16 + 8 * h8] = f.s8;
}

// ---------------------------------------------------------------------------
// Depthwise 3x3 SAME. grid (C, B, 2)
// ---------------------------------------------------------------------------
__global__ __launch_bounds__(256)
void dw_kernel(float* __restrict__ dst0, const float* __restrict__ src0,
               const float* __restrict__ k0w,
               float* __restrict__ dst1, const float* __restrict__ src1,
               const float* __restrict__ k1w)
{
    const int c = blockIdx.x, b = blockIdx.y;
    const float* src; const float* kw; float* dst;
    if (blockIdx.z == 0) { src = src0; kw = k0w; dst = dst0; }
    else                 { src = src1; kw = k1w; dst = dst1; }
    src += ((size_t)b * CCH + c) * NPIX;
    dst += ((size_t)b * CCH + c) * NPIX;

    float k[9];
    #pragma unroll
    for (int j = 0; j < 9; ++j) k[j] = kw[c * 9 + j];

    __shared__ float t[34][36];
    const int tid = threadIdx.x;
    for (int idx = tid; idx < 34 * 34; idx += 256) {
        int y = idx / 34, x = idx % 34;
        int gy = y - 1, gx = x - 1;
        t[y][x] = (gy >= 0 && gy < 32 && gx >= 0 && gx < 32)
                      ? src[gy * 32 + gx] : 0.f;
    }
    __syncthreads();
    const int x = tid % 32, y0 = tid / 32;
    #pragma unroll
    for (int q = 0; q < 4; ++q) {
        int y = y0 + 8 * q;
        float s = 0.f;
        #pragma unroll
        for (int dy = 0; dy < 3; ++dy)
            #pragma unroll
            for (int dx = 0; dx < 3; ++dx)
                s += t[y + dy][x + dx] * k[dy * 3 + dx];
        dst[y * 32 + x] = s;
    }
}

// ---------------------------------------------------------------------------
// MFMA dual-stream attention. Block: 256 thr / 4 waves; one (b, stream),
// 128 query cols (i), j-stages of 64 (two 32-j MFMA subtiles each).
// Sᵀ = Kᵀ·Q via 32x32x16 bf16; P kept in registers (pack + shfl_xor 32);
// PV = V·Pᵀ from LDS-staged, XOR-swizzled V (double-buffered).
// ---------------------------------------------------------------------------
__global__ __launch_bounds__(256)
void attn_mfma_kernel(float* __restrict__ Zh, float* __restrict__ Zm,
                      const __hip_bfloat16* __restrict__ Qt,
                      const __hip_bfloat16* __restrict__ Kht,
                      const __hip_bfloat16* __restrict__ Kmt,
                      const __hip_bfloat16* __restrict__ Vh,
                      const __hip_bfloat16* __restrict__ Vm)
{
    const int b  = blockIdx.y;
    const int i0 = blockIdx.x * 128;
    const __hip_bfloat16* Kt; const __hip_bfloat16* Vg; float* Og;
    if (blockIdx.z == 0) { Kt = Kht; Vg = Vh; Og = Zh; }
    else                 { Kt = Kmt; Vg = Vm; Og = Zm; }
    Kt += (size_t)b * NPIX * 16;
    Vg += (size_t)b * CCH * NPIX;
    Og += (size_t)b * CCH * NPIX;

    __shared__ __align__(16) char Vs[2][128 * 64 * 2];   // 2 x 16KB, swizzled bf16

    const int tid = threadIdx.x;
    const int w   = tid >> 6;       // wave -> i-subtile
    const int l   = tid & 63;
    const int l31 = l & 31;
    const int H   = l >> 5;

    // Q fragment (B operand), loaded once
    const __hip_bfloat16* Qb = Qt + (size_t)b * NPIX * 16;
    short8 qf = *(const short8*)&Qb[((size_t)(i0 + 32 * w + l31)) * 16 + 8 * H];

    f32x16 acc[4];
    #pragma unroll
    for (int ct = 0; ct < 4; ++ct)
        #pragma unroll
        for (int e = 0; e < 16; ++e) acc[ct][e] = 0.f;
    float l_acc = 0.f;

    // staging constants: 4 chunks of 16B per thread
    int cu[4], ldsoff[4]; size_t goff[4];
    #pragma unroll
    for (int u = 0; u < 4; ++u) {
        int idx = tid + 256 * u;
        cu[u] = idx >> 3;
        int jg = idx & 7;
        ldsoff[u] = cu[u] * 128 + ((jg ^ (cu[u] & 7)) << 4);
        goff[u]   = (size_t)cu[u] * NPIX + 8 * jg;
    }
    const int slotx_base = (l31 & 7);        // per-lane swizzle term for reads

    // prologue: prefetch stage 0 (V chunks + K fragments)
    short8 v0 = *(const short8*)&Vg[goff[0]];
    short8 v1 = *(const short8*)&Vg[goff[1]];
    short8 v2 = *(const short8*)&Vg[goff[2]];
    short8 v3 = *(const short8*)&Vg[goff[3]];
    short8 kf0 = *(const short8*)&Kt[(size_t)(0 + l31) * 16 + 8 * H];
    short8 kf1 = *(const short8*)&Kt[(size_t)(32 + l31) * 16 + 8 * H];

    for (int t = 0; t < 16; ++t) {
        char* buf = &Vs[t & 1][0];
        // write current staged regs to LDS (swizzled)
        *(short8*)(buf + ldsoff[0]) = v0;
        *(short8*)(buf + ldsoff[1]) = v1;
        *(short8*)(buf + ldsoff[2]) = v2;
        *(short8*)(buf + ldsoff[3]) = v3;

        // issue next-stage global loads (hide under compute)
        short8 kn0 = kf0, kn1 = kf1;
        if (t < 15) {
            const int jn = (t + 1) * 64;
            v0 = *(const short8*)&Vg[goff[0] + jn];
            v1 = *(const short8*)&Vg[goff[1] + jn];
            v2 = *(const short8*)&Vg[goff[2] + jn];
            v3 = *(const short8*)&Vg[goff[3] + jn];
            kn0 = *(const short8*)&Kt[(size_t)(jn + l31) * 16 + 8 * H];
            kn1 = *(const short8*)&Kt[(size_t)(jn + 32 + l31) * 16 + 8 * H];
        }
        __syncthreads();

        #pragma unroll
        for (int jt = 0; jt < 2; ++jt) {
            short8 kcur = (jt == 0) ? kf0 : kf1;
            f32x16 z;
            #pragma unroll
            for (int e = 0; e < 16; ++e) z[e] = 0.f;
            f32x16 s = __builtin_amdgcn_mfma_f32_32x32x16_bf16(kcur, qf, z, 0, 0, 0);

            float p[16];
            float ls = 0.f;
            #pragma unroll
            for (int r = 0; r < 16; ++r) { p[r] = __expf(s[r]); ls += p[r]; }
            l_acc += ls + __shfl_xor(ls, 32);

            unsigned w0[4], w1[4], x0[4], x1[4];
            #pragma unroll
            for (int g = 0; g < 4; ++g) {
                w0[g] = pack2bf(p[4 * g + 0], p[4 * g + 1]);
                w1[g] = pack2bf(p[4 * g + 2], p[4 * g + 3]);
            }
            #pragma unroll
            for (int g = 0; g < 4; ++g) {
                x0[g] = __shfl_xor(w0[g], 32);
                x1[g] = __shfl_xor(w1[g], 32);
            }
            #pragma unroll
            for (int js = 0; js < 2; ++js) {
                const int gA = 2 * js, gB = 2 * js + 1;
                Frag8 pb;
                pb.u[0] = H ? x0[gB] : w0[gA];
                pb.u[1] = H ? x1[gB] : w1[gA];
                pb.u[2] = H ? w0[gB] : x0[gA];
                pb.u[3] = H ? w1[gB] : x1[gA];
                const int slot = 4 * jt + 2 * js + H;
                const int sx   = (slot ^ slotx_base) << 4;
                #pragma unroll
                for (int ct = 0; ct < 4; ++ct) {
                    short8 vf = *(short8*)(buf + (32 * ct + l31) * 128 + sx);
                    acc[ct] = __builtin_amdgcn_mfma_f32_32x32x16_bf16(
                        vf, pb.s8, acc[ct], 0, 0, 0);
                }
            }
        }
        kf0 = kn0; kf1 = kn1;
    }

    const float linv = 1.0f / l_acc;
    const int ig = i0 + 32 * w + l31;
    #pragma unroll
    for (int ct = 0; ct < 4; ++ct) {
        #pragma unroll
        for (int r = 0; r < 16; ++r) {
            int c = 32 * ct + (r & 3) + 8 * (r >> 2) + 4 * H;
            Og[(size_t)c * NPIX + ig] = acc[ct][r] * linv;
        }
    }
}

// ---------------------------------------------------------------------------
__device__ __forceinline__ float sigf(float x) { return 1.f / (1.f + __expf(-x)); }

__global__ __launch_bounds__(256)
void combine_kernel(float* __restrict__ m_out, float* __restrict__ om,
                    const float* __restrict__ G1, const float* __restrict__ G2,
                    const float* __restrict__ G3, const float* __restrict__ mp)
{
    size_t idx = ((size_t)blockIdx.x * 256 + threadIdx.x) * 4;
    float4 a4 = *(const float4*)&G1[idx];
    float4 g4 = *(const float4*)&G2[idx];
    float4 o4 = *(const float4*)&G3[idx];
    float4 m4 = *(const float4*)&mp[idx];
    float ia[4] = {a4.x, a4.y, a4.z, a4.w};
    float ga[4] = {g4.x, g4.y, g4.z, g4.w};
    float oa[4] = {o4.x, o4.y, o4.z, o4.w};
    float ma[4] = {m4.x, m4.y, m4.z, m4.w};
    float mo[4], om4[4];
    #pragma unroll
    for (int j = 0; j < 4; ++j) {
        float it = sigf(ia[j]);
        float gt = tanhf(ga[j]);
        float ot = sigf(oa[j]);
        float mt = (1.f - it) * ma[j] + it * gt;
        mo[j]  = mt;
        om4[j] = ot * mt;
    }
    *(float4*)&m_out[idx] = make_float4(mo[0], mo[1], mo[2], mo[3]);
    *(float4*)&om[idx]    = make_float4(om4[0], om4[1], om4[2], om4[3]);
}

// ---------------------------------------------------------------------------
extern "C" void kernel_launch(void* const* d_in, const int* in_sizes, int n_in,
                              void* d_out, int out_size, void* d_ws, size_t ws_size,
                              hipStream_t stream)
{
    (void)in_sizes; (void)n_in; (void)out_size; (void)ws_size;
    const float* h_t    = (const float*)d_in[0];
    const float* m_prev = (const float*)d_in[1];
    const float* wq_h   = (const float*)d_in[2];
    const float* wk_h   = (const float*)d_in[3];
    const float* wv_h   = (const float*)d_in[4];
    const float* wk_m   = (const float*)d_in[5];
    const float* wv_m   = (const float*)d_in[6];
    const float* wz_w   = (const float*)d_in[7];
    const float* wz_b   = (const float*)d_in[8];
    const float* wmi_dw = (const float*)d_in[9];
    const float* wmi_pw = (const float*)d_in[10];
    const float* whi_dw = (const float*)d_in[11];
    const float* whi_pw = (const float*)d_in[12];
    const float* bi     = (const float*)d_in[13];
    const float* wmg_dw = (const float*)d_in[14];
    const float* wmg_pw = (const float*)d_in[15];
    const float* whg_dw = (const float*)d_in[16];
    const float* whg_pw = (const float*)d_in[17];
    const float* bg     = (const float*)d_in[18];
    const float* wmo_dw = (const float*)d_in[19];
    const float* wmo_pw = (const float*)d_in[20];
    const float* who_dw = (const float*)d_in[21];
    const float* who_pw = (const float*)d_in[22];
    const float* bo     = (const float*)d_in[23];
    const float* wf_w   = (const float*)d_in[24];
    const float* wf_b   = (const float*)d_in[25];

    float* out = (float*)d_out;               // [h_out | m_t]

    const size_t SQE = (size_t)BB * NPIX * CRED;   // 524288 elems
    const size_t SV  = (size_t)BB * CCH * NPIX;    // 4194304 elems

    __hip_bfloat16* Qt  = (__hip_bfloat16*)d_ws;
    __hip_bfloat16* Kht = Qt  + SQE;
    __hip_bfloat16* Kmt = Kht + SQE;
    __hip_bfloat16* Vhb = Kmt + SQE;
    __hip_bfloat16* Vmb = Vhb + SV;
    float* Zh = (float*)(Vmb + SV);
    float* Zm = Zh + SV;
    float* Ev = Zm + SV;   // Z
    float* Fv = Ev + SV;   // dw(Z,.) scratch, later om
    float* Gv = Fv + SV;   // dw(h_t,.) scratch
    float* Hv = Gv + SV;   // G3

    dim3 blk(256);

    // Q/K projections (transposed bf16) + V projections (bf16)
    qkproj_kernel<<<dim3(NPIX / 128, BB, 3), blk, 0, stream>>>(
        Qt, Kht, Kmt, h_t, m_prev, wq_h, wk_h, wk_m);
    pw_kernel<128, 64, true><<<dim3(NPIX / 64, BB), blk, 0, stream>>>(
        Vhb, h_t, wv_h, CCH, nullptr, nullptr, 0, nullptr, nullptr);
    pw_kernel<128, 64, true><<<dim3(NPIX / 64, BB), blk, 0, stream>>>(
        Vmb, m_prev, wv_m, CCH, nullptr, nullptr, 0, nullptr, nullptr);

    // dual attention (MFMA) -> Zh, Zm (f32)
    attn_mfma_kernel<<<dim3(NPIX / 128, BB, 2), blk, 0, stream>>>(
        Zh, Zm, Qt, Kht, Kmt, Vhb, Vmb);

    // Z = wz * [Zh; Zm] + wz_b -> Ev
    pw_kernel<128, 64, false><<<dim3(NPIX / 64, BB), blk, 0, stream>>>(
        Ev, Zh, wz_w, 2 * CCH, Zm, wz_w + CCH, 2 * CCH, wz_b, nullptr);

    // gates: i -> Zh, g -> Zm, o -> Hv
    dw_kernel<<<dim3(CCH, BB, 2), blk, 0, stream>>>(Fv, Ev, wmi_dw, Gv, h_t, whi_dw);
    pw_kernel<128, 64, false><<<dim3(NPIX / 64, BB), blk, 0, stream>>>(
        Zh, Fv, wmi_pw, CCH, Gv, whi_pw, CCH, bi, nullptr);
    dw_kernel<<<dim3(CCH, BB, 2), blk, 0, stream>>>(Fv, Ev, wmg_dw, Gv, h_t, whg_dw);
    pw_kernel<128, 64, false><<<dim3(NPIX / 64, BB), blk, 0, stream>>>(
        Zm, Fv, wmg_pw, CCH, Gv, whg_pw, CCH, bg, nullptr);
    dw_kernel<<<dim3(CCH, BB, 2), blk, 0, stream>>>(Fv, Ev, wmo_dw, Gv, h_t, who_dw);
    pw_kernel<128, 64, false><<<dim3(NPIX / 64, BB), blk, 0, stream>>>(
        Hv, Fv, wmo_pw, CCH, Gv, who_pw, CCH, bo, nullptr);

    // m_t -> out+SV ; om -> Fv
    combine_kernel<<<dim3(SV / 1024), blk, 0, stream>>>(
        out + SV, Fv, Zh, Zm, Hv, m_prev);

    // h_out = wf * om + wf_b + h_t -> out
    pw_kernel<128, 64, false><<<dim3(NPIX / 64, BB), blk, 0, stream>>>(
        out, Fv, wf_w, CCH, nullptr, nullptr, 0, wf_b, h_t);
}

// Round 4
// 364.769 us; speedup vs baseline: 2.6570x; 1.3540x over previous
//
#include <hip/hip_runtime.h>
#include <hip/hip_bf16.h>
#include <math.h>

#define BB   32
#define CCH  128
#define NPIX 1024
#define CRED 16

typedef __attribute__((ext_vector_type(8)))  short short8;
typedef __attribute__((ext_vector_type(16))) float f32x16;

union Frag8 { short8 s8; unsigned u[4]; };

__device__ __forceinline__ unsigned pack2bf(float lo, float hi) {
    union { __hip_bfloat16 h; unsigned short u; } a, b;
    a.h = __float2bfloat16(lo);
    b.h = __float2bfloat16(hi);
    return (unsigned)a.u | ((unsigned)b.u << 16);
}

// ---------------------------------------------------------------------------
// Weight pre-conversion: 11 slots of [128][128] bf16.
// slots: 0 wv_h, 1 wv_m, 2 wz[:, :128], 3 wz[:, 128:], 4 wmi_pw, 5 whi_pw,
//        6 wmg_pw, 7 whg_pw, 8 wmo_pw, 9 who_pw, 10 wf_w
// ---------------------------------------------------------------------------
__global__ __launch_bounds__(256)
void wcvt_kernel(__hip_bfloat16* __restrict__ dst,
                 const float* __restrict__ s0, const float* __restrict__ s1,
                 const float* __restrict__ wz,
                 const float* __restrict__ s4, const float* __restrict__ s5,
                 const float* __restrict__ s6, const float* __restrict__ s7,
                 const float* __restrict__ s8, const float* __restrict__ s9,
                 const float* __restrict__ s10)
{
    const int slot = blockIdx.y;
    const int e = (blockIdx.x * 256 + threadIdx.x) * 4;
    const float* src;
    size_t soff;
    if (slot == 2 || slot == 3) {
        const int o = e >> 7, c = e & 127;
        src = wz;
        soff = (size_t)o * 256 + (slot == 3 ? 128 : 0) + c;
    } else {
        switch (slot) {
            case 0: src = s0; break;  case 1: src = s1; break;
            case 4: src = s4; break;  case 5: src = s5; break;
            case 6: src = s6; break;  case 7: src = s7; break;
            case 8: src = s8; break;  case 9: src = s9; break;
            default: src = s10; break;
        }
        soff = e;
    }
    float4 v = *(const float4*)&src[soff];
    uint2 pk = make_uint2(pack2bf(v.x, v.y), pack2bf(v.z, v.w));
    *(uint2*)&dst[(size_t)slot * 16384 + e] = pk;
}

// ---------------------------------------------------------------------------
// MFMA pointwise GEMM. out[b][o][p] = sum_c W1[o][c]X1[b][c][p] (+W2·X2)
// (+bias) (+res).  Block: 256 thr / 4 waves; N-tile 64 pixels; wave -> 64ch x
// 32px quadrant.  X staged to LDS transposed bf16 [p][c], 8B-granule XOR
// swizzle; W fragments straight from global bf16 (L1/L2-hot).
// ---------------------------------------------------------------------------
__device__ __forceinline__ void stage_tile(char* buf, const float* Xb, int tid)
{
    const int p  = tid & 63;
    const int gb = tid >> 6;
    float xr[32];
    #pragma unroll
    for (int u = 0; u < 8; ++u) {
        const int c0 = (u * 4 + gb) * 4;
        #pragma unroll
        for (int j = 0; j < 4; ++j)
            xr[u * 4 + j] = Xb[(size_t)(c0 + j) * NPIX + p];
    }
    #pragma unroll
    for (int u = 0; u < 8; ++u) {
        const int g = u * 4 + gb;
        uint2 pk = make_uint2(pack2bf(xr[u * 4 + 0], xr[u * 4 + 1]),
                              pack2bf(xr[u * 4 + 2], xr[u * 4 + 3]));
        *(uint2*)(buf + p * 256 + ((g ^ (p & 31)) << 3)) = pk;
    }
}

__device__ __forceinline__ void compute_pass(const char* buf,
                                             const __hip_bfloat16* W,
                                             f32x16* acc,
                                             int l31, int H, int ntw, int mth)
{
    const int prow = (32 * ntw + l31) * 256;
    #pragma unroll
    for (int kt = 0; kt < 8; ++kt) {
        Frag8 bf_;
        const int g0 = 4 * kt + 2 * H;
        *(uint2*)&bf_.u[0] = *(const uint2*)(buf + prow + (((g0    ) ^ l31) << 3));
        *(uint2*)&bf_.u[2] = *(const uint2*)(buf + prow + (((g0 + 1) ^ l31) << 3));
        #pragma unroll
        for (int mi = 0; mi < 2; ++mi) {
            const int m = 32 * (2 * mth + mi) + l31;
            short8 af = *(const short8*)&W[(size_t)m * 128 + 16 * kt + 8 * H];
            acc[mi] = __builtin_amdgcn_mfma_f32_32x32x16_bf16(af, bf_.s8, acc[mi], 0, 0, 0);
        }
    }
}

template<bool TWO, bool BF16OUT>
__global__ __launch_bounds__(256)
void pw_mfma(void* __restrict__ outv,
             const float* __restrict__ X1, const __hip_bfloat16* __restrict__ W1,
             const float* __restrict__ X2, const __hip_bfloat16* __restrict__ W2,
             const float* __restrict__ bias, const float* __restrict__ res)
{
    __shared__ __align__(16) char Xs[2][16384];
    const int tid = threadIdx.x;
    const int b   = blockIdx.y;
    const int p0  = blockIdx.x * 64;
    const int l31 = tid & 31;
    const int H   = (tid & 63) >> 5;
    const int w   = tid >> 6;
    const int ntw = w & 1;
    const int mth = w >> 1;

    stage_tile(&Xs[0][0], X1 + (size_t)b * CCH * NPIX + p0, tid);
    if (TWO)
        stage_tile(&Xs[1][0], X2 + (size_t)b * CCH * NPIX + p0, tid);
    __syncthreads();

    f32x16 acc[2];
    #pragma unroll
    for (int mi = 0; mi < 2; ++mi)
        #pragma unroll
        for (int e = 0; e < 16; ++e) acc[mi][e] = 0.f;

    compute_pass(&Xs[0][0], W1, acc, l31, H, ntw, mth);
    if (TWO)
        compute_pass(&Xs[1][0], W2, acc, l31, H, ntw, mth);

    const int pg = p0 + 32 * ntw + l31;
    #pragma unroll
    for (int mi = 0; mi < 2; ++mi) {
        const int mtile = 2 * mth + mi;
        #pragma unroll
        for (int r = 0; r < 16; ++r) {
            const int m = 32 * mtile + (r & 3) + 8 * (r >> 2) + 4 * H;
            float v = acc[mi][r];
            if (bias) v += bias[m];
            const size_t off = ((size_t)b * CCH + m) * NPIX + pg;
            if (res) v += res[off];
            if (BF16OUT) ((__hip_bfloat16*)outv)[off] = __float2bfloat16(v);
            else         ((float*)outv)[off] = v;
        }
    }
}

// ---------------------------------------------------------------------------
// Q/K projection -> transposed bf16 [B][NPIX][16]. z: 0=Q(h), 1=Kh(h), 2=Km(m)
// ---------------------------------------------------------------------------
__global__ __launch_bounds__(256)
void qkproj_kernel(__hip_bfloat16* __restrict__ Qt,
                   __hip_bfloat16* __restrict__ Kht,
                   __hip_bfloat16* __restrict__ Kmt,
                   const float* __restrict__ h_t,
                   const float* __restrict__ m_prev,
                   const float* __restrict__ wq,
                   const float* __restrict__ wkh,
                   const float* __restrict__ wkm)
{
    const int b  = blockIdx.y;
    const int p0 = blockIdx.x * 128;
    const float* X; const float* W; __hip_bfloat16* Out;
    if (blockIdx.z == 0)      { X = h_t;    W = wq;  Out = Qt;  }
    else if (blockIdx.z == 1) { X = h_t;    W = wkh; Out = Kht; }
    else                      { X = m_prev; W = wkm; Out = Kmt; }

    __shared__ float Ws[16][128];
    __shared__ float Xs[32][132];
    const int tid = threadIdx.x;
    for (int i = tid; i < 16 * 128; i += 256)
        Ws[i / 128][i % 128] = W[i];

    const float* Xb = X + (size_t)b * CCH * NPIX;
    const int pl = tid & 127;
    const int h8 = tid >> 7;

    float acc[8];
    #pragma unroll
    for (int e = 0; e < 8; ++e) acc[e] = 0.f;

    for (int c0 = 0; c0 < CCH; c0 += 32) {
        __syncthreads();
        for (int idx = tid; idx < 32 * 32; idx += 256) {
            int r = idx >> 5, cp = (idx & 31) << 2;
            *(float4*)&Xs[r][cp] =
                *(const float4*)&Xb[(size_t)(c0 + r) * NPIX + p0 + cp];
        }
        __syncthreads();
        #pragma unroll 8
        for (int cc = 0; cc < 32; ++cc) {
            float xv = Xs[cc][pl];
            #pragma unroll
            for (int e = 0; e < 8; ++e)
                acc[e] += Ws[h8 * 8 + e][c0 + cc] * xv;
        }
    }

    Frag8 f;
    #pragma unroll
    for (int w = 0; w < 4; ++w)
        f.u[w] = pack2bf(acc[2 * w], acc[2 * w + 1]);
    *(short8*)&Out[((size_t)b * NPIX + p0 + pl) * 16 + 8 * h8] = f.s8;
}

// ---------------------------------------------------------------------------
// Depthwise 3x3 SAME. grid (C, B, 2)
// ---------------------------------------------------------------------------
__global__ __launch_bounds__(256)
void dw_kernel(float* __restrict__ dst0, const float* __restrict__ src0,
               const float* __restrict__ k0w,
               float* __restrict__ dst1, const float* __restrict__ src1,
               const float* __restrict__ k1w)
{
    const int c = blockIdx.x, b = blockIdx.y;
    const float* src; const float* kw; float* dst;
    if (blockIdx.z == 0) { src = src0; kw = k0w; dst = dst0; }
    else                 { src = src1; kw = k1w; dst = dst1; }
    src += ((size_t)b * CCH + c) * NPIX;
    dst += ((size_t)b * CCH + c) * NPIX;

    float k[9];
    #pragma unroll
    for (int j = 0; j < 9; ++j) k[j] = kw[c * 9 + j];

    __shared__ float t[34][36];
    const int tid = threadIdx.x;
    for (int idx = tid; idx < 34 * 34; idx += 256) {
        int y = idx / 34, x = idx % 34;
        int gy = y - 1, gx = x - 1;
        t[y][x] = (gy >= 0 && gy < 32 && gx >= 0 && gx < 32)
                      ? src[gy * 32 + gx] : 0.f;
    }
    __syncthreads();
    const int x = tid % 32, y0 = tid / 32;
    #pragma unroll
    for (int q = 0; q < 4; ++q) {
        int y = y0 + 8 * q;
        float s = 0.f;
        #pragma unroll
        for (int dy = 0; dy < 3; ++dy)
            #pragma unroll
            for (int dx = 0; dx < 3; ++dx)
                s += t[y + dy][x + dx] * k[dy * 3 + dx];
        dst[y * 32 + x] = s;
    }
}

// ---------------------------------------------------------------------------
// MFMA dual-stream attention (unchanged from round 1).
// ---------------------------------------------------------------------------
__global__ __launch_bounds__(256)
void attn_mfma_kernel(float* __restrict__ Zh, float* __restrict__ Zm,
                      const __hip_bfloat16* __restrict__ Qt,
                      const __hip_bfloat16* __restrict__ Kht,
                      const __hip_bfloat16* __restrict__ Kmt,
                      const __hip_bfloat16* __restrict__ Vh,
                      const __hip_bfloat16* __restrict__ Vm)
{
    const int b  = blockIdx.y;
    const int i0 = blockIdx.x * 128;
    const __hip_bfloat16* Kt; const __hip_bfloat16* Vg; float* Og;
    if (blockIdx.z == 0) { Kt = Kht; Vg = Vh; Og = Zh; }
    else                 { Kt = Kmt; Vg = Vm; Og = Zm; }
    Kt += (size_t)b * NPIX * 16;
    Vg += (size_t)b * CCH * NPIX;
    Og += (size_t)b * CCH * NPIX;

    __shared__ __align__(16) char Vs[2][128 * 64 * 2];

    const int tid = threadIdx.x;
    const int w   = tid >> 6;
    const int l   = tid & 63;
    const int l31 = l & 31;
    const int H   = l >> 5;

    const __hip_bfloat16* Qb = Qt + (size_t)b * NPIX * 16;
    short8 qf = *(const short8*)&Qb[((size_t)(i0 + 32 * w + l31)) * 16 + 8 * H];

    f32x16 acc[4];
    #pragma unroll
    for (int ct = 0; ct < 4; ++ct)
        #pragma unroll
        for (int e = 0; e < 16; ++e) acc[ct][e] = 0.f;
    float l_acc = 0.f;

    int cu[4], ldsoff[4]; size_t goff[4];
    #pragma unroll
    for (int u = 0; u < 4; ++u) {
        int idx = tid + 256 * u;
        cu[u] = idx >> 3;
        int jg = idx & 7;
        ldsoff[u] = cu[u] * 128 + ((jg ^ (cu[u] & 7)) << 4);
        goff[u]   = (size_t)cu[u] * NPIX + 8 * jg;
    }
    const int slotx_base = (l31 & 7);

    short8 v0 = *(const short8*)&Vg[goff[0]];
    short8 v1 = *(const short8*)&Vg[goff[1]];
    short8 v2 = *(const short8*)&Vg[goff[2]];
    short8 v3 = *(const short8*)&Vg[goff[3]];
    short8 kf0 = *(const short8*)&Kt[(size_t)(0 + l31) * 16 + 8 * H];
    short8 kf1 = *(const short8*)&Kt[(size_t)(32 + l31) * 16 + 8 * H];

    for (int t = 0; t < 16; ++t) {
        char* buf = &Vs[t & 1][0];
        *(short8*)(buf + ldsoff[0]) = v0;
        *(short8*)(buf + ldsoff[1]) = v1;
        *(short8*)(buf + ldsoff[2]) = v2;
        *(short8*)(buf + ldsoff[3]) = v3;

        short8 kn0 = kf0, kn1 = kf1;
        if (t < 15) {
            const int jn = (t + 1) * 64;
            v0 = *(const short8*)&Vg[goff[0] + jn];
            v1 = *(const short8*)&Vg[goff[1] + jn];
            v2 = *(const short8*)&Vg[goff[2] + jn];
            v3 = *(const short8*)&Vg[goff[3] + jn];
            kn0 = *(const short8*)&Kt[(size_t)(jn + l31) * 16 + 8 * H];
            kn1 = *(const short8*)&Kt[(size_t)(jn + 32 + l31) * 16 + 8 * H];
        }
        __syncthreads();

        #pragma unroll
        for (int jt = 0; jt < 2; ++jt) {
            short8 kcur = (jt == 0) ? kf0 : kf1;
            f32x16 z;
            #pragma unroll
            for (int e = 0; e < 16; ++e) z[e] = 0.f;
            f32x16 s = __builtin_amdgcn_mfma_f32_32x32x16_bf16(kcur, qf, z, 0, 0, 0);

            float p[16];
            float ls = 0.f;
            #pragma unroll
            for (int r = 0; r < 16; ++r) { p[r] = __expf(s[r]); ls += p[r]; }
            l_acc += ls + __shfl_xor(ls, 32);

            unsigned w0[4], w1[4], x0[4], x1[4];
            #pragma unroll
            for (int g = 0; g < 4; ++g) {
                w0[g] = pack2bf(p[4 * g + 0], p[4 * g + 1]);
                w1[g] = pack2bf(p[4 * g + 2], p[4 * g + 3]);
            }
            #pragma unroll
            for (int g = 0; g < 4; ++g) {
                x0[g] = __shfl_xor(w0[g], 32);
                x1[g] = __shfl_xor(w1[g], 32);
            }
            #pragma unroll
            for (int js = 0; js < 2; ++js) {
                const int gA = 2 * js, gB = 2 * js + 1;
                Frag8 pb;
                pb.u[0] = H ? x0[gB] : w0[gA];
                pb.u[1] = H ? x1[gB] : w1[gA];
                pb.u[2] = H ? w0[gB] : x0[gA];
                pb.u[3] = H ? w1[gB] : x1[gA];
                const int slot = 4 * jt + 2 * js + H;
                const int sx   = (slot ^ slotx_base) << 4;
                #pragma unroll
                for (int ct = 0; ct < 4; ++ct) {
                    short8 vf = *(short8*)(buf + (32 * ct + l31) * 128 + sx);
                    acc[ct] = __builtin_amdgcn_mfma_f32_32x32x16_bf16(
                        vf, pb.s8, acc[ct], 0, 0, 0);
                }
            }
        }
        kf0 = kn0; kf1 = kn1;
    }

    const float linv = 1.0f / l_acc;
    const int ig = i0 + 32 * w + l31;
    #pragma unroll
    for (int ct = 0; ct < 4; ++ct) {
        #pragma unroll
        for (int r = 0; r < 16; ++r) {
            int c = 32 * ct + (r & 3) + 8 * (r >> 2) + 4 * H;
            Og[(size_t)c * NPIX + ig] = acc[ct][r] * linv;
        }
    }
}

// ---------------------------------------------------------------------------
__device__ __forceinline__ float sigf(float x) { return 1.f / (1.f + __expf(-x)); }

__global__ __launch_bounds__(256)
void combine_kernel(float* __restrict__ m_out, float* __restrict__ om,
                    const float* __restrict__ G1, const float* __restrict__ G2,
                    const float* __restrict__ G3, const float* __restrict__ mp)
{
    size_t idx = ((size_t)blockIdx.x * 256 + threadIdx.x) * 4;
    float4 a4 = *(const float4*)&G1[idx];
    float4 g4 = *(const float4*)&G2[idx];
    float4 o4 = *(const float4*)&G3[idx];
    float4 m4 = *(const float4*)&mp[idx];
    float ia[4] = {a4.x, a4.y, a4.z, a4.w};
    float ga[4] = {g4.x, g4.y, g4.z, g4.w};
    float oa[4] = {o4.x, o4.y, o4.z, o4.w};
    float ma[4] = {m4.x, m4.y, m4.z, m4.w};
    float mo[4], om4[4];
    #pragma unroll
    for (int j = 0; j < 4; ++j) {
        float it = sigf(ia[j]);
        float gt = tanhf(ga[j]);
        float ot = sigf(oa[j]);
        float mt = (1.f - it) * ma[j] + it * gt;
        mo[j]  = mt;
        om4[j] = ot * mt;
    }
    *(float4*)&m_out[idx] = make_float4(mo[0], mo[1], mo[2], mo[3]);
    *(float4*)&om[idx]    = make_float4(om4[0], om4[1], om4[2], om4[3]);
}

// ---------------------------------------------------------------------------
extern "C" void kernel_launch(void* const* d_in, const int* in_sizes, int n_in,
                              void* d_out, int out_size, void* d_ws, size_t ws_size,
                              hipStream_t stream)
{
    (void)in_sizes; (void)n_in; (void)out_size; (void)ws_size;
    const float* h_t    = (const float*)d_in[0];
    const float* m_prev = (const float*)d_in[1];
    const float* wq_h   = (const float*)d_in[2];
    const float* wk_h   = (const float*)d_in[3];
    const float* wv_h   = (const float*)d_in[4];
    const float* wk_m   = (const float*)d_in[5];
    const float* wv_m   = (const float*)d_in[6];
    const float* wz_w   = (const float*)d_in[7];
    const float* wz_b   = (const float*)d_in[8];
    const float* wmi_dw = (const float*)d_in[9];
    const float* wmi_pw = (const float*)d_in[10];
    const float* whi_dw = (const float*)d_in[11];
    const float* whi_pw = (const float*)d_in[12];
    const float* bi     = (const float*)d_in[13];
    const float* wmg_dw = (const float*)d_in[14];
    const float* wmg_pw = (const float*)d_in[15];
    const float* whg_dw = (const float*)d_in[16];
    const float* whg_pw = (const float*)d_in[17];
    const float* bg     = (const float*)d_in[18];
    const float* wmo_dw = (const float*)d_in[19];
    const float* wmo_pw = (const float*)d_in[20];
    const float* who_dw = (const float*)d_in[21];
    const float* who_pw = (const float*)d_in[22];
    const float* bo     = (const float*)d_in[23];
    const float* wf_w   = (const float*)d_in[24];
    const float* wf_b   = (const float*)d_in[25];

    float* out = (float*)d_out;               // [h_out | m_t]

    const size_t SQE = (size_t)BB * NPIX * CRED;   // 524288 elems
    const size_t SV  = (size_t)BB * CCH * NPIX;    // 4194304 elems

    __hip_bfloat16* Wb  = (__hip_bfloat16*)d_ws;   // 11*16384 = 180224 elems
    __hip_bfloat16* Qt  = Wb + 184320;
    __hip_bfloat16* Kht = Qt  + SQE;
    __hip_bfloat16* Kmt = Kht + SQE;
    __hip_bfloat16* Vhb = Kmt + SQE;
    __hip_bfloat16* Vmb = Vhb + SV;
    float* Zh = (float*)(Vmb + SV);
    float* Zm = Zh + SV;
    float* Ev = Zm + SV;   // Z
    float* Fv = Ev + SV;   // dw(Z,.) scratch, later om
    float* Gv = Fv + SV;   // dw(h_t,.) scratch
    float* Hv = Gv + SV;   // G3

    dim3 blk(256);
    dim3 pwg(NPIX / 64, BB);

    // weight conversion (bf16 slots)
    wcvt_kernel<<<dim3(16, 11), blk, 0, stream>>>(
        Wb, wv_h, wv_m, wz_w, wmi_pw, whi_pw, wmg_pw, whg_pw, wmo_pw, who_pw, wf_w);

    // Q/K projections (transposed bf16) + V projections (bf16, MFMA)
    qkproj_kernel<<<dim3(NPIX / 128, BB, 3), blk, 0, stream>>>(
        Qt, Kht, Kmt, h_t, m_prev, wq_h, wk_h, wk_m);
    pw_mfma<false, true><<<pwg, blk, 0, stream>>>(
        Vhb, h_t, Wb + 0 * 16384, nullptr, nullptr, nullptr, nullptr);
    pw_mfma<false, true><<<pwg, blk, 0, stream>>>(
        Vmb, m_prev, Wb + 1 * 16384, nullptr, nullptr, nullptr, nullptr);

    // dual attention (MFMA) -> Zh, Zm (f32)
    attn_mfma_kernel<<<dim3(NPIX / 128, BB, 2), blk, 0, stream>>>(
        Zh, Zm, Qt, Kht, Kmt, Vhb, Vmb);

    // Z = wz * [Zh; Zm] + wz_b -> Ev
    pw_mfma<true, false><<<pwg, blk, 0, stream>>>(
        Ev, Zh, Wb + 2 * 16384, Zm, Wb + 3 * 16384, wz_b, nullptr);

    // gates: i -> Zh, g -> Zm, o -> Hv
    dw_kernel<<<dim3(CCH, BB, 2), blk, 0, stream>>>(Fv, Ev, wmi_dw, Gv, h_t, whi_dw);
    pw_mfma<true, false><<<pwg, blk, 0, stream>>>(
        Zh, Fv, Wb + 4 * 16384, Gv, Wb + 5 * 16384, bi, nullptr);
    dw_kernel<<<dim3(CCH, BB, 2), blk, 0, stream>>>(Fv, Ev, wmg_dw, Gv, h_t, whg_dw);
    pw_mfma<true, false><<<pwg, blk, 0, stream>>>(
        Zm, Fv, Wb + 6 * 16384, Gv, Wb + 7 * 16384, bg, nullptr);
    dw_kernel<<<dim3(CCH, BB, 2), blk, 0, stream>>>(Fv, Ev, wmo_dw, Gv, h_t, who_dw);
    pw_mfma<true, false><<<pwg, blk, 0, stream>>>(
        Hv, Fv, Wb + 8 * 16384, Gv, Wb + 9 * 16384, bo, nullptr);

    // m_t -> out+SV ; om -> Fv
    combine_kernel<<<dim3(SV / 1024), blk, 0, stream>>>(
        out + SV, Fv, Zh, Zm, Hv, m_prev);

    // h_out = wf * om + wf_b + h_t -> out
    pw_mfma<false, false><<<pwg, blk, 0, stream>>>(
        out, Fv, Wb + 10 * 16384, nullptr, nullptr, wf_b, h_t);
}

// Round 6
// 301.247 us; speedup vs baseline: 3.2173x; 1.2109x over previous
//
#include <hip/hip_runtime.h>
#include <hip/hip_bf16.h>
#include <math.h>

#define BB   32
#define CCH  128
#define NPIX 1024
#define CRED 16

typedef __attribute__((ext_vector_type(8)))  short short8;
typedef __attribute__((ext_vector_type(16))) float f32x16;

union Frag8 { short8 s8; unsigned u[4]; };

__device__ __forceinline__ unsigned pack2bf(float lo, float hi) {
    union { __hip_bfloat16 h; unsigned short u; } a, b;
    a.h = __float2bfloat16(lo);
    b.h = __float2bfloat16(hi);
    return (unsigned)a.u | ((unsigned)b.u << 16);
}

// ---------------------------------------------------------------------------
// Weight pre-conversion: 11 slots of [128][128] bf16.
// slots: 0 wv_h, 1 wv_m, 2 wz[:, :128], 3 wz[:, 128:], 4 wmi_pw, 5 whi_pw,
//        6 wmg_pw, 7 whg_pw, 8 wmo_pw, 9 who_pw, 10 wf_w
// ---------------------------------------------------------------------------
__global__ __launch_bounds__(256)
void wcvt_kernel(__hip_bfloat16* __restrict__ dst,
                 const float* __restrict__ s0, const float* __restrict__ s1,
                 const float* __restrict__ wz,
                 const float* __restrict__ s4, const float* __restrict__ s5,
                 const float* __restrict__ s6, const float* __restrict__ s7,
                 const float* __restrict__ s8, const float* __restrict__ s9,
                 const float* __restrict__ s10)
{
    const int slot = blockIdx.y;
    const int e = (blockIdx.x * 256 + threadIdx.x) * 4;
    const float* src;
    size_t soff;
    if (slot == 2 || slot == 3) {
        const int o = e >> 7, c = e & 127;
        src = wz;
        soff = (size_t)o * 256 + (slot == 3 ? 128 : 0) + c;
    } else {
        switch (slot) {
            case 0: src = s0; break;  case 1: src = s1; break;
            case 4: src = s4; break;  case 5: src = s5; break;
            case 6: src = s6; break;  case 7: src = s7; break;
            case 8: src = s8; break;  case 9: src = s9; break;
            default: src = s10; break;
        }
        soff = e;
    }
    float4 v = *(const float4*)&src[soff];
    uint2 pk = make_uint2(pack2bf(v.x, v.y), pack2bf(v.z, v.w));
    *(uint2*)&dst[(size_t)slot * 16384 + e] = pk;
}

// ---------------------------------------------------------------------------
// LDS staging for MFMA GEMMs: tile [64 px][128 ch] bf16, 8B-granule XOR
// swizzle (granule g at byte p*256 + ((g ^ (p&31))<<3)).
// ---------------------------------------------------------------------------
__device__ __forceinline__ void stage_tile(char* buf, const float* Xb, int tid)
{
    const int p  = tid & 63;
    const int gb = tid >> 6;
    float xr[32];
    #pragma unroll
    for (int u = 0; u < 8; ++u) {
        const int c0 = (u * 4 + gb) * 4;
        #pragma unroll
        for (int j = 0; j < 4; ++j)
            xr[u * 4 + j] = Xb[(size_t)(c0 + j) * NPIX + p];
    }
    #pragma unroll
    for (int u = 0; u < 8; ++u) {
        const int g = u * 4 + gb;
        uint2 pk = make_uint2(pack2bf(xr[u * 4 + 0], xr[u * 4 + 1]),
                              pack2bf(xr[u * 4 + 2], xr[u * 4 + 3]));
        *(uint2*)(buf + p * 256 + ((g ^ (p & 31)) << 3)) = pk;
    }
}

__device__ __forceinline__ void stage_tile_bf16(char* buf,
                                                const __hip_bfloat16* Xb, int tid)
{
    const unsigned short* Xu = (const unsigned short*)Xb;
    const int p  = tid & 63;
    const int gb = tid >> 6;
    #pragma unroll
    for (int u = 0; u < 8; ++u) {
        const int g  = u * 4 + gb;
        const int c0 = g * 4;
        unsigned e0 = Xu[(size_t)(c0 + 0) * NPIX + p];
        unsigned e1 = Xu[(size_t)(c0 + 1) * NPIX + p];
        unsigned e2 = Xu[(size_t)(c0 + 2) * NPIX + p];
        unsigned e3 = Xu[(size_t)(c0 + 3) * NPIX + p];
        uint2 pk = make_uint2(e0 | (e1 << 16), e2 | (e3 << 16));
        *(uint2*)(buf + p * 256 + ((g ^ (p & 31)) << 3)) = pk;
    }
}

__device__ __forceinline__ void compute_pass(const char* buf,
                                             const __hip_bfloat16* W,
                                             f32x16* acc,
                                             int l31, int H, int ntw, int mth)
{
    const int prow = (32 * ntw + l31) * 256;
    #pragma unroll
    for (int kt = 0; kt < 8; ++kt) {
        Frag8 bf_;
        const int g0 = 4 * kt + 2 * H;
        *(uint2*)&bf_.u[0] = *(const uint2*)(buf + prow + (((g0    ) ^ l31) << 3));
        *(uint2*)&bf_.u[2] = *(const uint2*)(buf + prow + (((g0 + 1) ^ l31) << 3));
        #pragma unroll
        for (int mi = 0; mi < 2; ++mi) {
            const int m = 32 * (2 * mth + mi) + l31;
            short8 af = *(const short8*)&W[(size_t)m * 128 + 16 * kt + 8 * H];
            acc[mi] = __builtin_amdgcn_mfma_f32_32x32x16_bf16(af, bf_.s8, acc[mi], 0, 0, 0);
        }
    }
}

// ---------------------------------------------------------------------------
// MFMA pointwise GEMM. out[b][o][p] = sum_c W1[o][c]X1[b][c][p] (+W2·X2)
// (+bias) (+res).  Block: 256 thr / 4 waves; N-tile 64 px.
// ---------------------------------------------------------------------------
template<bool TWO, bool BF16IN, bool BF16OUT>
__global__ __launch_bounds__(256)
void pw_mfma(void* __restrict__ outv,
             const void* __restrict__ X1, const __hip_bfloat16* __restrict__ W1,
             const void* __restrict__ X2, const __hip_bfloat16* __restrict__ W2,
             const float* __restrict__ bias, const float* __restrict__ res)
{
    __shared__ __align__(16) char Xs[2][16384];
    const int tid = threadIdx.x;
    const int b   = blockIdx.y;
    const int p0  = blockIdx.x * 64;
    const int l31 = tid & 31;
    const int H   = (tid & 63) >> 5;
    const int w   = tid >> 6;
    const int ntw = w & 1;
    const int mth = w >> 1;
    const size_t boff = (size_t)b * CCH * NPIX + p0;

    if (BF16IN) stage_tile_bf16(&Xs[0][0], (const __hip_bfloat16*)X1 + boff, tid);
    else        stage_tile     (&Xs[0][0], (const float*)X1 + boff, tid);
    if (TWO) {
        if (BF16IN) stage_tile_bf16(&Xs[1][0], (const __hip_bfloat16*)X2 + boff, tid);
        else        stage_tile     (&Xs[1][0], (const float*)X2 + boff, tid);
    }
    __syncthreads();

    f32x16 acc[2];
    #pragma unroll
    for (int mi = 0; mi < 2; ++mi)
        #pragma unroll
        for (int e = 0; e < 16; ++e) acc[mi][e] = 0.f;

    compute_pass(&Xs[0][0], W1, acc, l31, H, ntw, mth);
    if (TWO)
        compute_pass(&Xs[1][0], W2, acc, l31, H, ntw, mth);

    const int pg = p0 + 32 * ntw + l31;
    #pragma unroll
    for (int mi = 0; mi < 2; ++mi) {
        const int mtile = 2 * mth + mi;
        #pragma unroll
        for (int r = 0; r < 16; ++r) {
            const int m = 32 * mtile + (r & 3) + 8 * (r >> 2) + 4 * H;
            float v = acc[mi][r];
            if (bias) v += bias[m];
            const size_t off = ((size_t)b * CCH + m) * NPIX + pg;
            if (res) v += res[off];
            if (BF16OUT) ((__hip_bfloat16*)outv)[off] = __float2bfloat16(v);
            else         ((float*)outv)[off] = v;
        }
    }
}

// ---------------------------------------------------------------------------
// Q/K projection -> transposed bf16 [B][NPIX][16]. z: 0=Q(h), 1=Kh(h), 2=Km(m)
// ---------------------------------------------------------------------------
__global__ __launch_bounds__(256)
void qkproj_kernel(__hip_bfloat16* __restrict__ Qt,
                   __hip_bfloat16* __restrict__ Kht,
                   __hip_bfloat16* __restrict__ Kmt,
                   const float* __restrict__ h_t,
                   const float* __restrict__ m_prev,
                   const float* __restrict__ wq,
                   const float* __restrict__ wkh,
                   const float* __restrict__ wkm)
{
    const int b  = blockIdx.y;
    const int p0 = blockIdx.x * 128;
    const float* X; const float* W; __hip_bfloat16* Out;
    if (blockIdx.z == 0)      { X = h_t;    W = wq;  Out = Qt;  }
    else if (blockIdx.z == 1) { X = h_t;    W = wkh; Out = Kht; }
    else                      { X = m_prev; W = wkm; Out = Kmt; }

    __shared__ float Ws[16][128];
    __shared__ float Xs[32][132];
    const int tid = threadIdx.x;
    for (int i = tid; i < 16 * 128; i += 256)
        Ws[i / 128][i % 128] = W[i];

    const float* Xb = X + (size_t)b * CCH * NPIX;
    const int pl = tid & 127;
    const int h8 = tid >> 7;

    float acc[8];
    #pragma unroll
    for (int e = 0; e < 8; ++e) acc[e] = 0.f;

    for (int c0 = 0; c0 < CCH; c0 += 32) {
        __syncthreads();
        for (int idx = tid; idx < 32 * 32; idx += 256) {
            int r = idx >> 5, cp = (idx & 31) << 2;
            *(float4*)&Xs[r][cp] =
                *(const float4*)&Xb[(size_t)(c0 + r) * NPIX + p0 + cp];
        }
        __syncthreads();
        #pragma unroll 8
        for (int cc = 0; cc < 32; ++cc) {
            float xv = Xs[cc][pl];
            #pragma unroll
            for (int e = 0; e < 8; ++e)
                acc[e] += Ws[h8 * 8 + e][c0 + cc] * xv;
        }
    }

    Frag8 f;
    #pragma unroll
    for (int w = 0; w < 4; ++w)
        f.u[w] = pack2bf(acc[2 * w], acc[2 * w + 1]);
    *(short8*)&Out[((size_t)b * NPIX + p0 + pl) * 16 + 8 * h8] = f.s8;
}

// ---------------------------------------------------------------------------
// All six depthwise 3x3 convs in one dispatch. grid (C, B, 2):
//  z=0: src=Z,  kernels {wmi,wmg,wmo} -> D0,D1,D2  (bf16)
//  z=1: src=h_t, kernels {whi,whg,who} -> D3,D4,D5  (bf16)
// ---------------------------------------------------------------------------
__global__ __launch_bounds__(256)
void dw6_kernel(__hip_bfloat16* __restrict__ D, size_t SVe,
                const float* __restrict__ Z, const float* __restrict__ h_t,
                const float* __restrict__ wmi, const float* __restrict__ wmg,
                const float* __restrict__ wmo,
                const float* __restrict__ whi, const float* __restrict__ whg,
                const float* __restrict__ who)
{
    const int c = blockIdx.x, b = blockIdx.y;
    const float* src; const float *kaw, *kbw, *kcw;
    __hip_bfloat16* dbase;
    if (blockIdx.z == 0) { src = Z;   kaw = wmi; kbw = wmg; kcw = wmo; dbase = D; }
    else                 { src = h_t; kaw = whi; kbw = whg; kcw = who; dbase = D + 3 * SVe; }
    const size_t chan = ((size_t)b * CCH + c) * NPIX;
    src += chan;
    __hip_bfloat16* d0 = dbase + chan;
    __hip_bfloat16* d1 = d0 + SVe;
    __hip_bfloat16* d2 = d1 + SVe;

    float ka[9], kb[9], kc[9];
    #pragma unroll
    for (int j = 0; j < 9; ++j) {
        ka[j] = kaw[c * 9 + j];
        kb[j] = kbw[c * 9 + j];
        kc[j] = kcw[c * 9 + j];
    }

    __shared__ float t[34][36];
    const int tid = threadIdx.x;
    for (int idx = tid; idx < 34 * 34; idx += 256) {
        int y = idx / 34, x = idx % 34;
        int gy = y - 1, gx = x - 1;
        t[y][x] = (gy >= 0 && gy < 32 && gx >= 0 && gx < 32)
                      ? src[gy * 32 + gx] : 0.f;
    }
    __syncthreads();
    const int x = tid % 32, y0 = tid / 32;
    #pragma unroll
    for (int q = 0; q < 4; ++q) {
        int y = y0 + 8 * q;
        float s0 = 0.f, s1 = 0.f, s2 = 0.f;
        #pragma unroll
        for (int dy = 0; dy < 3; ++dy)
            #pragma unroll
            for (int dx = 0; dx < 3; ++dx) {
                float tv = t[y + dy][x + dx];
                s0 += tv * ka[dy * 3 + dx];
                s1 += tv * kb[dy * 3 + dx];
                s2 += tv * kc[dy * 3 + dx];
            }
        d0[y * 32 + x] = __float2bfloat16(s0);
        d1[y * 32 + x] = __float2bfloat16(s1);
        d2[y * 32 + x] = __float2bfloat16(s2);
    }
}

// ---------------------------------------------------------------------------
// Fused gate GEMMs + LSTM combine.  Per block: 64 pixels, all 128 out-ch.
// 6 ping-pong staged LDS tiles: s={D0·W4, D3·W5 -> i | D1·W6, D4·W7 -> g |
// D2·W8, D5·W9 -> o}; epilogue computes m_t=(1-i)m_prev+i·g, om=o·m_t.
// ---------------------------------------------------------------------------
__global__ __launch_bounds__(256)
void gates_mfma(float* __restrict__ mt_out, float* __restrict__ om_out,
                const __hip_bfloat16* __restrict__ D, size_t SVe,
                const __hip_bfloat16* __restrict__ Wg,
                const float* __restrict__ bi, const float* __restrict__ bg,
                const float* __restrict__ bo, const float* __restrict__ mp)
{
    __shared__ __align__(16) char Xs[2][16384];
    const int tid = threadIdx.x;
    const int b   = blockIdx.y;
    const int p0  = blockIdx.x * 64;
    const int l31 = tid & 31;
    const int H   = (tid & 63) >> 5;
    const int w   = tid >> 6;
    const int ntw = w & 1;
    const int mth = w >> 1;
    const size_t boff = (size_t)b * CCH * NPIX + p0;

    const int ds[6] = {0, 3, 1, 4, 2, 5};

    f32x16 acc[6];
    #pragma unroll
    for (int a = 0; a < 6; ++a)
        #pragma unroll
        for (int e = 0; e < 16; ++e) acc[a][e] = 0.f;

    stage_tile_bf16(&Xs[0][0], D + (size_t)ds[0] * SVe + boff, tid);
    __syncthreads();

    #pragma unroll
    for (int s = 0; s < 6; ++s) {
        if (s < 5)
            stage_tile_bf16(&Xs[(s + 1) & 1][0], D + (size_t)ds[s + 1] * SVe + boff, tid);
        compute_pass(&Xs[s & 1][0], Wg + (size_t)s * 16384,
                     &acc[2 * (s >> 1)], l31, H, ntw, mth);
        __syncthreads();
    }

    const int pg = p0 + 32 * ntw + l31;
    #pragma unroll
    for (int mi = 0; mi < 2; ++mi) {
        const int mtile = 2 * mth + mi;
        #pragma unroll
        for (int r = 0; r < 16; ++r) {
            const int m = 32 * mtile + (r & 3) + 8 * (r >> 2) + 4 * H;
            const size_t off = ((size_t)b * CCH + m) * NPIX + pg;
            float it = 1.f / (1.f + __expf(-(acc[0 + mi][r] + bi[m])));
            float gt = tanhf(acc[2 + mi][r] + bg[m]);
            float ot = 1.f / (1.f + __expf(-(acc[4 + mi][r] + bo[m])));
            float mpv = mp[off];
            float mt = (1.f - it) * mpv + it * gt;
            mt_out[off] = mt;
            om_out[off] = ot * mt;
        }
    }
}

// ---------------------------------------------------------------------------
// MFMA dual-stream attention (bf16 Z output).
// ---------------------------------------------------------------------------
__global__ __launch_bounds__(256)
void attn_mfma_kernel(__hip_bfloat16* __restrict__ Zh,
                      __hip_bfloat16* __restrict__ Zm,
                      const __hip_bfloat16* __restrict__ Qt,
                      const __hip_bfloat16* __restrict__ Kht,
                      const __hip_bfloat16* __restrict__ Kmt,
                      const __hip_bfloat16* __restrict__ Vh,
                      const __hip_bfloat16* __restrict__ Vm)
{
    const int b  = blockIdx.y;
    const int i0 = blockIdx.x * 128;
    const __hip_bfloat16* Kt; const __hip_bfloat16* Vg; __hip_bfloat16* Og;
    if (blockIdx.z == 0) { Kt = Kht; Vg = Vh; Og = Zh; }
    else                 { Kt = Kmt; Vg = Vm; Og = Zm; }
    Kt += (size_t)b * NPIX * 16;
    Vg += (size_t)b * CCH * NPIX;
    Og += (size_t)b * CCH * NPIX;

    __shared__ __align__(16) char Vs[2][128 * 64 * 2];

    const int tid = threadIdx.x;
    const int w   = tid >> 6;
    const int l   = tid & 63;
    const int l31 = l & 31;
    const int H   = l >> 5;

    const __hip_bfloat16* Qb = Qt + (size_t)b * NPIX * 16;
    short8 qf = *(const short8*)&Qb[((size_t)(i0 + 32 * w + l31)) * 16 + 8 * H];

    f32x16 acc[4];
    #pragma unroll
    for (int ct = 0; ct < 4; ++ct)
        #pragma unroll
        for (int e = 0; e < 16; ++e) acc[ct][e] = 0.f;
    float l_acc = 0.f;

    int cu[4], ldsoff[4]; size_t goff[4];
    #pragma unroll
    for (int u = 0; u < 4; ++u) {
        int idx = tid + 256 * u;
        cu[u] = idx >> 3;
        int jg = idx & 7;
        ldsoff[u] = cu[u] * 128 + ((jg ^ (cu[u] & 7)) << 4);
        goff[u]   = (size_t)cu[u] * NPIX + 8 * jg;
    }
    const int slotx_base = (l31 & 7);

    short8 v0 = *(const short8*)&Vg[goff[0]];
    short8 v1 = *(const short8*)&Vg[goff[1]];
    short8 v2 = *(const short8*)&Vg[goff[2]];
    short8 v3 = *(const short8*)&Vg[goff[3]];
    short8 kf0 = *(const short8*)&Kt[(size_t)(0 + l31) * 16 + 8 * H];
    short8 kf1 = *(const short8*)&Kt[(size_t)(32 + l31) * 16 + 8 * H];

    for (int t = 0; t < 16; ++t) {
        char* buf = &Vs[t & 1][0];
        *(short8*)(buf + ldsoff[0]) = v0;
        *(short8*)(buf + ldsoff[1]) = v1;
        *(short8*)(buf + ldsoff[2]) = v2;
        *(short8*)(buf + ldsoff[3]) = v3;

        short8 kn0 = kf0, kn1 = kf1;
        if (t < 15) {
            const int jn = (t + 1) * 64;
            v0 = *(const short8*)&Vg[goff[0] + jn];
            v1 = *(const short8*)&Vg[goff[1] + jn];
            v2 = *(const short8*)&Vg[goff[2] + jn];
            v3 = *(const short8*)&Vg[goff[3] + jn];
            kn0 = *(const short8*)&Kt[(size_t)(jn + l31) * 16 + 8 * H];
            kn1 = *(const short8*)&Kt[(size_t)(jn + 32 + l31) * 16 + 8 * H];
        }
        __syncthreads();

        #pragma unroll
        for (int jt = 0; jt < 2; ++jt) {
            short8 kcur = (jt == 0) ? kf0 : kf1;
            f32x16 z;
            #pragma unroll
            for (int e = 0; e < 16; ++e) z[e] = 0.f;
            f32x16 s = __builtin_amdgcn_mfma_f32_32x32x16_bf16(kcur, qf, z, 0, 0, 0);

            float p[16];
            float ls = 0.f;
            #pragma unroll
            for (int r = 0; r < 16; ++r) { p[r] = __expf(s[r]); ls += p[r]; }
            l_acc += ls + __shfl_xor(ls, 32);

            unsigned w0[4], w1[4], x0[4], x1[4];
            #pragma unroll
            for (int g = 0; g < 4; ++g) {
                w0[g] = pack2bf(p[4 * g + 0], p[4 * g + 1]);
                w1[g] = pack2bf(p[4 * g + 2], p[4 * g + 3]);
            }
            #pragma unroll
            for (int g = 0; g < 4; ++g) {
                x0[g] = __shfl_xor(w0[g], 32);
                x1[g] = __shfl_xor(w1[g], 32);
            }
            #pragma unroll
            for (int js = 0; js < 2; ++js) {
                const int gA = 2 * js, gB = 2 * js + 1;
                Frag8 pb;
                pb.u[0] = H ? x0[gB] : w0[gA];
                pb.u[1] = H ? x1[gB] : w1[gA];
                pb.u[2] = H ? w0[gB] : x0[gA];
                pb.u[3] = H ? w1[gB] : x1[gA];
                const int slot = 4 * jt + 2 * js + H;
                const int sx   = (slot ^ slotx_base) << 4;
                #pragma unroll
                for (int ct = 0; ct < 4; ++ct) {
                    short8 vf = *(short8*)(buf + (32 * ct + l31) * 128 + sx);
                    acc[ct] = __builtin_amdgcn_mfma_f32_32x32x16_bf16(
                        vf, pb.s8, acc[ct], 0, 0, 0);
                }
            }
        }
        kf0 = kn0; kf1 = kn1;
    }

    const float linv = 1.0f / l_acc;
    const int ig = i0 + 32 * w + l31;
    #pragma unroll
    for (int ct = 0; ct < 4; ++ct) {
        #pragma unroll
        for (int r = 0; r < 16; ++r) {
            int c = 32 * ct + (r & 3) + 8 * (r >> 2) + 4 * H;
            Og[(size_t)c * NPIX + ig] = __float2bfloat16(acc[ct][r] * linv);
        }
    }
}

// ---------------------------------------------------------------------------
extern "C" void kernel_launch(void* const* d_in, const int* in_sizes, int n_in,
                              void* d_out, int out_size, void* d_ws, size_t ws_size,
                              hipStream_t stream)
{
    (void)in_sizes; (void)n_in; (void)out_size; (void)ws_size;
    const float* h_t    = (const float*)d_in[0];
    const float* m_prev = (const float*)d_in[1];
    const float* wq_h   = (const float*)d_in[2];
    const float* wk_h   = (const float*)d_in[3];
    const float* wv_h   = (const float*)d_in[4];
    const float* wk_m   = (const float*)d_in[5];
    const float* wv_m   = (const float*)d_in[6];
    const float* wz_w   = (const float*)d_in[7];
    const float* wz_b   = (const float*)d_in[8];
    const float* wmi_dw = (const float*)d_in[9];
    const float* wmi_pw = (const float*)d_in[10];
    const float* whi_dw = (const float*)d_in[11];
    const float* whi_pw = (const float*)d_in[12];
    const float* bi     = (const float*)d_in[13];
    const float* wmg_dw = (const float*)d_in[14];
    const float* wmg_pw = (const float*)d_in[15];
    const float* whg_dw = (const float*)d_in[16];
    const float* whg_pw = (const float*)d_in[17];
    const float* bg     = (const float*)d_in[18];
    const float* wmo_dw = (const float*)d_in[19];
    const float* wmo_pw = (const float*)d_in[20];
    const float* who_dw = (const float*)d_in[21];
    const float* who_pw = (const float*)d_in[22];
    const float* bo     = (const float*)d_in[23];
    const float* wf_w   = (const float*)d_in[24];
    const float* wf_b   = (const float*)d_in[25];

    float* out = (float*)d_out;               // [h_out | m_t]

    const size_t SQE = (size_t)BB * NPIX * CRED;   // 524288 elems
    const size_t SV  = (size_t)BB * CCH * NPIX;    // 4194304 elems

    __hip_bfloat16* Wb  = (__hip_bfloat16*)d_ws;   // 11*16384 bf16
    __hip_bfloat16* Qt  = Wb + 184320;
    __hip_bfloat16* Kht = Qt  + SQE;
    __hip_bfloat16* Kmt = Kht + SQE;
    __hip_bfloat16* Vhb = Kmt + SQE;
    __hip_bfloat16* Vmb = Vhb + SV;
    __hip_bfloat16* Zhb = Vmb + SV;
    __hip_bfloat16* Zmb = Zhb + SV;
    __hip_bfloat16* Dd  = Zmb + SV;                // 6 x SV bf16 (dw outputs)
    float* Ev = (float*)(Dd + 6 * SV);             // Z (f32)
    float* Fv = Ev + SV;                           // om (f32)

    dim3 blk(256);
    dim3 pwg(NPIX / 64, BB);

    // weight conversion (bf16 slots)
    wcvt_kernel<<<dim3(16, 11), blk, 0, stream>>>(
        Wb, wv_h, wv_m, wz_w, wmi_pw, whi_pw, wmg_pw, whg_pw, wmo_pw, who_pw, wf_w);

    // Q/K projections (transposed bf16) + V projections (bf16, MFMA)
    qkproj_kernel<<<dim3(NPIX / 128, BB, 3), blk, 0, stream>>>(
        Qt, Kht, Kmt, h_t, m_prev, wq_h, wk_h, wk_m);
    pw_mfma<false, false, true><<<pwg, blk, 0, stream>>>(
        Vhb, h_t, Wb + 0 * 16384, nullptr, nullptr, nullptr, nullptr);
    pw_mfma<false, false, true><<<pwg, blk, 0, stream>>>(
        Vmb, m_prev, Wb + 1 * 16384, nullptr, nullptr, nullptr, nullptr);

    // dual attention (MFMA) -> Zh, Zm (bf16)
    attn_mfma_kernel<<<dim3(NPIX / 128, BB, 2), blk, 0, stream>>>(
        Zhb, Zmb, Qt, Kht, Kmt, Vhb, Vmb);

    // Z = wz * [Zh; Zm] + wz_b -> Ev (f32)
    pw_mfma<true, true, false><<<pwg, blk, 0, stream>>>(
        Ev, Zhb, Wb + 2 * 16384, Zmb, Wb + 3 * 16384, wz_b, nullptr);

    // all six depthwise convs -> Dd[0..5] (bf16)
    dw6_kernel<<<dim3(CCH, BB, 2), blk, 0, stream>>>(
        Dd, SV, Ev, h_t, wmi_dw, wmg_dw, wmo_dw, whi_dw, whg_dw, who_dw);

    // fused gate GEMMs + combine: m_t -> out+SV, om -> Fv
    gates_mfma<<<pwg, blk, 0, stream>>>(
        out + SV, Fv, Dd, SV, Wb + 4 * 16384, bi, bg, bo, m_prev);

    // h_out = wf * om + wf_b + h_t -> out
    pw_mfma<false, false, false><<<pwg, blk, 0, stream>>>(
        out, Fv, Wb + 10 * 16384, nullptr, nullptr, wf_b, h_t);
}

// Round 10
// 288.501 us; speedup vs baseline: 3.3594x; 1.0442x over previous
//
#include <hip/hip_runtime.h>
#include <hip/hip_bf16.h>
#include <math.h>

#define BB   32
#define CCH  128
#define NPIX 1024
#define CRED 16

typedef __attribute__((ext_vector_type(8)))  short short8;
typedef __attribute__((ext_vector_type(16))) float f32x16;

union Frag8 { short8 s8; unsigned u[4]; };

__device__ __forceinline__ unsigned pack2bf(float lo, float hi) {
    union { __hip_bfloat16 h; unsigned short u; } a, b;
    a.h = __float2bfloat16(lo);
    b.h = __float2bfloat16(hi);
    return (unsigned)a.u | ((unsigned)b.u << 16);
}

// ---------------------------------------------------------------------------
// Weight pre-conversion: 11 slots of [128][128] bf16.
// slots: 0 wv_h, 1 wv_m, 2 wz[:, :128], 3 wz[:, 128:], 4 wmi_pw, 5 whi_pw,
//        6 wmg_pw, 7 whg_pw, 8 wmo_pw, 9 who_pw, 10 wf_w
// ---------------------------------------------------------------------------
__global__ __launch_bounds__(256)
void wcvt_kernel(__hip_bfloat16* __restrict__ dst,
                 const float* __restrict__ s0, const float* __restrict__ s1,
                 const float* __restrict__ wz,
                 const float* __restrict__ s4, const float* __restrict__ s5,
                 const float* __restrict__ s6, const float* __restrict__ s7,
                 const float* __restrict__ s8, const float* __restrict__ s9,
                 const float* __restrict__ s10)
{
    const int slot = blockIdx.y;
    const int e = (blockIdx.x * 256 + threadIdx.x) * 4;
    const float* src;
    size_t soff;
    if (slot == 2 || slot == 3) {
        const int o = e >> 7, c = e & 127;
        src = wz;
        soff = (size_t)o * 256 + (slot == 3 ? 128 : 0) + c;
    } else {
        switch (slot) {
            case 0: src = s0; break;  case 1: src = s1; break;
            case 4: src = s4; break;  case 5: src = s5; break;
            case 6: src = s6; break;  case 7: src = s7; break;
            case 8: src = s8; break;  case 9: src = s9; break;
            default: src = s10; break;
        }
        soff = e;
    }
    float4 v = *(const float4*)&src[soff];
    uint2 pk = make_uint2(pack2bf(v.x, v.y), pack2bf(v.z, v.w));
    *(uint2*)&dst[(size_t)slot * 16384 + e] = pk;
}

// ---------------------------------------------------------------------------
// LDS staging for 64px MFMA GEMMs: tile [64 px][128 ch] bf16, 8B-granule XOR
// swizzle (granule g at byte p*256 + ((g ^ (p&31))<<3)).
// ---------------------------------------------------------------------------
__device__ __forceinline__ void stage_tile(char* buf, const float* Xb, int tid)
{
    const int p  = tid & 63;
    const int gb = tid >> 6;
    float xr[32];
    #pragma unroll
    for (int u = 0; u < 8; ++u) {
        const int c0 = (u * 4 + gb) * 4;
        #pragma unroll
        for (int j = 0; j < 4; ++j)
            xr[u * 4 + j] = Xb[(size_t)(c0 + j) * NPIX + p];
    }
    #pragma unroll
    for (int u = 0; u < 8; ++u) {
        const int g = u * 4 + gb;
        uint2 pk = make_uint2(pack2bf(xr[u * 4 + 0], xr[u * 4 + 1]),
                              pack2bf(xr[u * 4 + 2], xr[u * 4 + 3]));
        *(uint2*)(buf + p * 256 + ((g ^ (p & 31)) << 3)) = pk;
    }
}

__device__ __forceinline__ void stage_tile_bf16(char* buf,
                                                const __hip_bfloat16* Xb, int tid)
{
    const unsigned short* Xu = (const unsigned short*)Xb;
    const int p  = tid & 63;
    const int gb = tid >> 6;
    #pragma unroll
    for (int u = 0; u < 8; ++u) {
        const int g  = u * 4 + gb;
        const int c0 = g * 4;
        unsigned e0 = Xu[(size_t)(c0 + 0) * NPIX + p];
        unsigned e1 = Xu[(size_t)(c0 + 1) * NPIX + p];
        unsigned e2 = Xu[(size_t)(c0 + 2) * NPIX + p];
        unsigned e3 = Xu[(size_t)(c0 + 3) * NPIX + p];
        uint2 pk = make_uint2(e0 | (e1 << 16), e2 | (e3 << 16));
        *(uint2*)(buf + p * 256 + ((g ^ (p & 31)) << 3)) = pk;
    }
}

__device__ __forceinline__ void compute_pass(const char* buf,
                                             const __hip_bfloat16* W,
                                             f32x16* acc,
                                             int l31, int H, int ntw, int mth)
{
    const int prow = (32 * ntw + l31) * 256;
    #pragma unroll
    for (int kt = 0; kt < 8; ++kt) {
        Frag8 bf_;
        const int g0 = 4 * kt + 2 * H;
        *(uint2*)&bf_.u[0] = *(const uint2*)(buf + prow + (((g0    ) ^ l31) << 3));
        *(uint2*)&bf_.u[2] = *(const uint2*)(buf + prow + (((g0 + 1) ^ l31) << 3));
        #pragma unroll
        for (int mi = 0; mi < 2; ++mi) {
            const int m = 32 * (2 * mth + mi) + l31;
            short8 af = *(const short8*)&W[(size_t)m * 128 + 16 * kt + 8 * H];
            acc[mi] = __builtin_amdgcn_mfma_f32_32x32x16_bf16(af, bf_.s8, acc[mi], 0, 0, 0);
        }
    }
}

// ---------------------------------------------------------------------------
// MFMA pointwise GEMM (64px tiles). out[b][o][p] = sum_c W1[o][c]X1[b][c][p]
// (+W2·X2) (+bias) (+res).
// ---------------------------------------------------------------------------
template<bool TWO, bool BF16IN, bool BF16OUT>
__global__ __launch_bounds__(256)
void pw_mfma(void* __restrict__ outv,
             const void* __restrict__ X1, const __hip_bfloat16* __restrict__ W1,
             const void* __restrict__ X2, const __hip_bfloat16* __restrict__ W2,
             const float* __restrict__ bias, const float* __restrict__ res)
{
    __shared__ __align__(16) char Xs[2][16384];
    const int tid = threadIdx.x;
    const int b   = blockIdx.y;
    const int p0  = blockIdx.x * 64;
    const int l31 = tid & 31;
    const int H   = (tid & 63) >> 5;
    const int w   = tid >> 6;
    const int ntw = w & 1;
    const int mth = w >> 1;
    const size_t boff = (size_t)b * CCH * NPIX + p0;

    if (BF16IN) stage_tile_bf16(&Xs[0][0], (const __hip_bfloat16*)X1 + boff, tid);
    else        stage_tile     (&Xs[0][0], (const float*)X1 + boff, tid);
    if (TWO) {
        if (BF16IN) stage_tile_bf16(&Xs[1][0], (const __hip_bfloat16*)X2 + boff, tid);
        else        stage_tile     (&Xs[1][0], (const float*)X2 + boff, tid);
    }
    __syncthreads();

    f32x16 acc[2];
    #pragma unroll
    for (int mi = 0; mi < 2; ++mi)
        #pragma unroll
        for (int e = 0; e < 16; ++e) acc[mi][e] = 0.f;

    compute_pass(&Xs[0][0], W1, acc, l31, H, ntw, mth);
    if (TWO)
        compute_pass(&Xs[1][0], W2, acc, l31, H, ntw, mth);

    const int pg = p0 + 32 * ntw + l31;
    #pragma unroll
    for (int mi = 0; mi < 2; ++mi) {
        const int mtile = 2 * mth + mi;
        #pragma unroll
        for (int r = 0; r < 16; ++r) {
            const int m = 32 * mtile + (r & 3) + 8 * (r >> 2) + 4 * H;
            float v = acc[mi][r];
            if (bias) v += bias[m];
            const size_t off = ((size_t)b * CCH + m) * NPIX + pg;
            if (res) v += res[off];
            if (BF16OUT) ((__hip_bfloat16*)outv)[off] = __float2bfloat16(v);
            else         ((float*)outv)[off] = v;
        }
    }
}

// ---------------------------------------------------------------------------
// Q/K projection -> transposed bf16 [B][NPIX][16]. z: 0=Q(h), 1=Kh(h), 2=Km(m)
// ---------------------------------------------------------------------------
__global__ __launch_bounds__(256)
void qkproj_kernel(__hip_bfloat16* __restrict__ Qt,
                   __hip_bfloat16* __restrict__ Kht,
                   __hip_bfloat16* __restrict__ Kmt,
                   const float* __restrict__ h_t,
                   const float* __restrict__ m_prev,
                   const float* __restrict__ wq,
                   const float* __restrict__ wkh,
                   const float* __restrict__ wkm)
{
    const int b  = blockIdx.y;
    const int p0 = blockIdx.x * 128;
    const float* X; const float* W; __hip_bfloat16* Out;
    if (blockIdx.z == 0)      { X = h_t;    W = wq;  Out = Qt;  }
    else if (blockIdx.z == 1) { X = h_t;    W = wkh; Out = Kht; }
    else                      { X = m_prev; W = wkm; Out = Kmt; }

    __shared__ float Ws[16][128];
    __shared__ float Xs[32][132];
    const int tid = threadIdx.x;
    for (int i = tid; i < 16 * 128; i += 256)
        Ws[i / 128][i % 128] = W[i];

    const float* Xb = X + (size_t)b * CCH * NPIX;
    const int pl = tid & 127;
    const int h8 = tid >> 7;

    float acc[8];
    #pragma unroll
    for (int e = 0; e < 8; ++e) acc[e] = 0.f;

    for (int c0 = 0; c0 < CCH; c0 += 32) {
        __syncthreads();
        for (int idx = tid; idx < 32 * 32; idx += 256) {
            int r = idx >> 5, cp = (idx & 31) << 2;
            *(float4*)&Xs[r][cp] =
                *(const float4*)&Xb[(size_t)(c0 + r) * NPIX + p0 + cp];
        }
        __syncthreads();
        #pragma unroll 8
        for (int cc = 0; cc < 32; ++cc) {
            float xv = Xs[cc][pl];
            #pragma unroll
            for (int e = 0; e < 8; ++e)
                acc[e] += Ws[h8 * 8 + e][c0 + cc] * xv;
        }
    }

    Frag8 f;
    #pragma unroll
    for (int w = 0; w < 4; ++w)
        f.u[w] = pack2bf(acc[2 * w], acc[2 * w + 1]);
    *(short8*)&Out[((size_t)b * NPIX + p0 + pl) * 16 + 8 * h8] = f.s8;
}

// ---------------------------------------------------------------------------
// All six depthwise 3x3 convs in one dispatch. grid (C, B, 2).
// Output layout: D[s][b][y][c][x] (tile-contiguous bf16: each (b,y) slice is
// a contiguous [128 c][32 x] = 8 KB block, so gates3 can stage with short8).
// ---------------------------------------------------------------------------
__global__ __launch_bounds__(256)
void dw6_kernel(__hip_bfloat16* __restrict__ D, size_t SVe,
                const float* __restrict__ Z, const float* __restrict__ h_t,
                const float* __restrict__ wmi, const float* __restrict__ wmg,
                const float* __restrict__ wmo,
                const float* __restrict__ whi, const float* __restrict__ whg,
                const float* __restrict__ who)
{
    const int c = blockIdx.x, b = blockIdx.y;
    const float* src; const float *kaw, *kbw, *kcw;
    __hip_bfloat16* dbase;
    if (blockIdx.z == 0) { src = Z;   kaw = wmi; kbw = wmg; kcw = wmo; dbase = D; }
    else                 { src = h_t; kaw = whi; kbw = whg; kcw = who; dbase = D + 3 * SVe; }
    src += ((size_t)b * CCH + c) * NPIX;

    float ka[9], kb[9], kc[9];
    #pragma unroll
    for (int j = 0; j < 9; ++j) {
        ka[j] = kaw[c * 9 + j];
        kb[j] = kbw[c * 9 + j];
        kc[j] = kcw[c * 9 + j];
    }

    __shared__ float t[34][36];
    const int tid = threadIdx.x;
    for (int idx = tid; idx < 34 * 34; idx += 256) {
        int y = idx / 34, x = idx % 34;
        int gy = y - 1, gx = x - 1;
        t[y][x] = (gy >= 0 && gy < 32 && gx >= 0 && gx < 32)
                      ? src[gy * 32 + gx] : 0.f;
    }
    __syncthreads();
    const int x = tid % 32, y0 = tid / 32;
    #pragma unroll
    for (int q = 0; q < 4; ++q) {
        int y = y0 + 8 * q;
        float s0 = 0.f, s1 = 0.f, s2 = 0.f;
        #pragma unroll
        for (int dy = 0; dy < 3; ++dy)
            #pragma unroll
            for (int dx = 0; dx < 3; ++dx) {
                float tv = t[y + dy][x + dx];
                s0 += tv * ka[dy * 3 + dx];
                s1 += tv * kb[dy * 3 + dx];
                s2 += tv * kc[dy * 3 + dx];
            }
        // [b][y][c][x] layout
        const size_t o = ((size_t)(b * 32 + y) * CCH + c) * 32 + x;
        dbase[o]           = __float2bfloat16(s0);
        dbase[SVe + o]     = __float2bfloat16(s1);
        dbase[2 * SVe + o] = __float2bfloat16(s2);
    }
}

// ---------------------------------------------------------------------------
// gates3: fused gate GEMMs + LSTM combine + final GEMM.
// Block: 256 thr / 4 waves; one (b, image-row y) = 32 px, all 128 out-ch.
// All 6 D-tiles prefetched into LDS before ONE barrier (one latency, not 6);
// 48 MFMA/wave; gate nonlinearities; om restaged to LDS (bf16, swizzled);
// +8 MFMA with wf; h_out = . + wf_b + h_t written directly.
// ---------------------------------------------------------------------------
__device__ __forceinline__ void pass32(const char* buf,
                                       const __hip_bfloat16* W,
                                       f32x16* acc, int l31, int H, int wv)
{
    const int prow = l31 * 256;
    #pragma unroll
    for (int kt = 0; kt < 8; ++kt) {
        Frag8 bf_;
        const int g0 = 4 * kt + 2 * H;
        *(uint2*)&bf_.u[0] = *(const uint2*)(buf + prow + (((g0    ) ^ l31) << 3));
        *(uint2*)&bf_.u[2] = *(const uint2*)(buf + prow + (((g0 + 1) ^ l31) << 3));
        const int m = 32 * wv + l31;
        short8 af = *(const short8*)&W[(size_t)m * 128 + 16 * kt + 8 * H];
        *acc = __builtin_amdgcn_mfma_f32_32x32x16_bf16(af, bf_.s8, *acc, 0, 0, 0);
    }
}

__global__ __launch_bounds__(256)
void gates3_kernel(float* __restrict__ mt_out, float* __restrict__ hout,
                   const __hip_bfloat16* __restrict__ D, size_t SVe,
                   const __hip_bfloat16* __restrict__ Wg,      // slots 4..9
                   const __hip_bfloat16* __restrict__ Wf,      // slot 10
                   const float* __restrict__ bi, const float* __restrict__ bg,
                   const float* __restrict__ bo, const float* __restrict__ wfb,
                   const float* __restrict__ mp, const float* __restrict__ h_t)
{
    __shared__ __align__(16) char Xs[6][8192];
    const int tid = threadIdx.x;
    const int y   = blockIdx.x;          // image row = 32-px tile
    const int b   = blockIdx.y;
    const int l31 = tid & 31;
    const int H   = (tid & 63) >> 5;
    const int wv  = tid >> 6;            // wave -> m-tile
    const size_t tbase = (size_t)(b * 32 + y) * 4096;   // elems into each slot

    // ---- stage all six tiles; loads coalesced short8, one barrier ----
    const int cs = tid >> 1;             // 0..127 (channel row)
    const int ph = (tid & 1) << 4;       // 0 / 16 (pixel half)
    const int gs = cs >> 2;              // c-granule 0..31
    const int cb = (cs & 3) << 1;        // byte offset within granule
    #pragma unroll
    for (int s = 0; s < 6; ++s) {
        const unsigned short* src =
            (const unsigned short*)(D + (size_t)s * SVe + tbase + cs * 32 + ph);
        short8 va = *(const short8*)(src);
        short8 vb = *(const short8*)(src + 8);
        char* buf = &Xs[s][0];
        #pragma unroll
        for (int j = 0; j < 8; ++j) {
            const int pa = ph + j, pb2 = ph + 8 + j;
            *(unsigned short*)(buf + pa  * 256 + ((gs ^ pa)  << 3) + cb) =
                (unsigned short)va[j];
            *(unsigned short*)(buf + pb2 * 256 + ((gs ^ pb2) << 3) + cb) =
                (unsigned short)vb[j];
        }
    }

    // prefetch m_prev for the combine (hides under staging/MFMA)
    const int pg = (y << 5) + l31;
    float mpv[16];
    #pragma unroll
    for (int r = 0; r < 16; ++r) {
        const int m = 32 * wv + (r & 3) + 8 * (r >> 2) + 4 * H;
        mpv[r] = mp[((size_t)b * CCH + m) * NPIX + pg];
    }

    __syncthreads();

    f32x16 aI, aG, aO;
    #pragma unroll
    for (int e = 0; e < 16; ++e) { aI[e] = 0.f; aG[e] = 0.f; aO[e] = 0.f; }

    pass32(&Xs[0][0], Wg + 0 * 16384, &aI, l31, H, wv);   // dw(Z,i) · wmi_pw
    pass32(&Xs[3][0], Wg + 1 * 16384, &aI, l31, H, wv);   // dw(h,i) · whi_pw
    pass32(&Xs[1][0], Wg + 2 * 16384, &aG, l31, H, wv);   // dw(Z,g) · wmg_pw
    pass32(&Xs[4][0], Wg + 3 * 16384, &aG, l31, H, wv);   // dw(h,g) · whg_pw
    pass32(&Xs[2][0], Wg + 4 * 16384, &aO, l31, H, wv);   // dw(Z,o) · wmo_pw
    pass32(&Xs[5][0], Wg + 5 * 16384, &aO, l31, H, wv);   // dw(h,o) · who_pw

    // ---- combine ----
    float om[16];
    #pragma unroll
    for (int r = 0; r < 16; ++r) {
        const int m = 32 * wv + (r & 3) + 8 * (r >> 2) + 4 * H;
        const size_t off = ((size_t)b * CCH + m) * NPIX + pg;
        float it = 1.f / (1.f + __expf(-(aI[r] + bi[m])));
        float gt = tanhf(aG[r] + bg[m]);
        float ot = 1.f / (1.f + __expf(-(aO[r] + bo[m])));
        float mpv_r = mpv[r];
        float mt = (1.f - it) * mpv_r + it * gt;
        mt_out[off] = mt;
        om[r] = ot * mt;
    }

    __syncthreads();                     // all waves done reading Xs
    // restage om -> Xs[0] (X-tile layout: granule g of 4 consecutive m)
    #pragma unroll
    for (int q = 0; q < 4; ++q) {
        const int g = 8 * wv + 2 * q + H;
        uint2 pk = make_uint2(pack2bf(om[4 * q + 0], om[4 * q + 1]),
                              pack2bf(om[4 * q + 2], om[4 * q + 3]));
        *(uint2*)(&Xs[0][0] + l31 * 256 + ((g ^ l31) << 3)) = pk;
    }
    __syncthreads();

    f32x16 aF;
    #pragma unroll
    for (int e = 0; e < 16; ++e) aF[e] = 0.f;
    pass32(&Xs[0][0], Wf, &aF, l31, H, wv);

    #pragma unroll
    for (int r = 0; r < 16; ++r) {
        const int m = 32 * wv + (r & 3) + 8 * (r >> 2) + 4 * H;
        const size_t off = ((size_t)b * CCH + m) * NPIX + pg;
        hout[off] = aF[r] + wfb[m] + h_t[off];
    }
}

// ---------------------------------------------------------------------------
// MFMA dual-stream attention (bf16 Z output).
// ---------------------------------------------------------------------------
__global__ __launch_bounds__(256)
void attn_mfma_kernel(__hip_bfloat16* __restrict__ Zh,
                      __hip_bfloat16* __restrict__ Zm,
                      const __hip_bfloat16* __restrict__ Qt,
                      const __hip_bfloat16* __restrict__ Kht,
                      const __hip_bfloat16* __restrict__ Kmt,
                      const __hip_bfloat16* __restrict__ Vh,
                      const __hip_bfloat16* __restrict__ Vm)
{
    const int b  = blockIdx.y;
    const int i0 = blockIdx.x * 128;
    const __hip_bfloat16* Kt; const __hip_bfloat16* Vg; __hip_bfloat16* Og;
    if (blockIdx.z == 0) { Kt = Kht; Vg = Vh; Og = Zh; }
    else                 { Kt = Kmt; Vg = Vm; Og = Zm; }
    Kt += (size_t)b * NPIX * 16;
    Vg += (size_t)b * CCH * NPIX;
    Og += (size_t)b * CCH * NPIX;

    __shared__ __align__(16) char Vs[2][128 * 64 * 2];

    const int tid = threadIdx.x;
    const int w   = tid >> 6;
    const int l   = tid & 63;
    const int l31 = l & 31;
    const int H   = l >> 5;

    const __hip_bfloat16* Qb = Qt + (size_t)b * NPIX * 16;
    short8 qf = *(const short8*)&Qb[((size_t)(i0 + 32 * w + l31)) * 16 + 8 * H];

    f32x16 acc[4];
    #pragma unroll
    for (int ct = 0; ct < 4; ++ct)
        #pragma unroll
        for (int e = 0; e < 16; ++e) acc[ct][e] = 0.f;
    float l_acc = 0.f;

    int cu[4], ldsoff[4]; size_t goff[4];
    #pragma unroll
    for (int u = 0; u < 4; ++u) {
        int idx = tid + 256 * u;
        cu[u] = idx >> 3;
        int jg = idx & 7;
        ldsoff[u] = cu[u] * 128 + ((jg ^ (cu[u] & 7)) << 4);
        goff[u]   = (size_t)cu[u] * NPIX + 8 * jg;
    }
    const int slotx_base = (l31 & 7);

    short8 v0 = *(const short8*)&Vg[goff[0]];
    short8 v1 = *(const short8*)&Vg[goff[1]];
    short8 v2 = *(const short8*)&Vg[goff[2]];
    short8 v3 = *(const short8*)&Vg[goff[3]];
    short8 kf0 = *(const short8*)&Kt[(size_t)(0 + l31) * 16 + 8 * H];
    short8 kf1 = *(const short8*)&Kt[(size_t)(32 + l31) * 16 + 8 * H];

    for (int t = 0; t < 16; ++t) {
        char* buf = &Vs[t & 1][0];
        *(short8*)(buf + ldsoff[0]) = v0;
        *(short8*)(buf + ldsoff[1]) = v1;
        *(short8*)(buf + ldsoff[2]) = v2;
        *(short8*)(buf + ldsoff[3]) = v3;

        short8 kn0 = kf0, kn1 = kf1;
        if (t < 15) {
            const int jn = (t + 1) * 64;
            v0 = *(const short8*)&Vg[goff[0] + jn];
            v1 = *(const short8*)&Vg[goff[1] + jn];
            v2 = *(const short8*)&Vg[goff[2] + jn];
            v3 = *(const short8*)&Vg[goff[3] + jn];
            kn0 = *(const short8*)&Kt[(size_t)(jn + l31) * 16 + 8 * H];
            kn1 = *(const short8*)&Kt[(size_t)(jn + 32 + l31) * 16 + 8 * H];
        }
        __syncthreads();

        #pragma unroll
        for (int jt = 0; jt < 2; ++jt) {
            short8 kcur = (jt == 0) ? kf0 : kf1;
            f32x16 z;
            #pragma unroll
            for (int e = 0; e < 16; ++e) z[e] = 0.f;
            f32x16 s = __builtin_amdgcn_mfma_f32_32x32x16_bf16(kcur, qf, z, 0, 0, 0);

            float p[16];
            float ls = 0.f;
            #pragma unroll
            for (int r = 0; r < 16; ++r) { p[r] = __expf(s[r]); ls += p[r]; }
            l_acc += ls + __shfl_xor(ls, 32);

            unsigned w0[4], w1[4], x0[4], x1[4];
            #pragma unroll
            for (int g = 0; g < 4; ++g) {
                w0[g] = pack2bf(p[4 * g + 0], p[4 * g + 1]);
                w1[g] = pack2bf(p[4 * g + 2], p[4 * g + 3]);
            }
            #pragma unroll
            for (int g = 0; g < 4; ++g) {
                x0[g] = __shfl_xor(w0[g], 32);
                x1[g] = __shfl_xor(w1[g], 32);
            }
            #pragma unroll
            for (int js = 0; js < 2; ++js) {
                const int gA = 2 * js, gB = 2 * js + 1;
                Frag8 pb;
                pb.u[0] = H ? x0[gB] : w0[gA];
                pb.u[1] = H ? x1[gB] : w1[gA];
                pb.u[2] = H ? w0[gB] : x0[gA];
                pb.u[3] = H ? w1[gB] : x1[gA];
                const int slot = 4 * jt + 2 * js + H;
                const int sx   = (slot ^ slotx_base) << 4;
                #pragma unroll
                for (int ct = 0; ct < 4; ++ct) {
                    short8 vf = *(short8*)(buf + (32 * ct + l31) * 128 + sx);
                    acc[ct] = __builtin_amdgcn_mfma_f32_32x32x16_bf16(
                        vf, pb.s8, acc[ct], 0, 0, 0);
                }
            }
        }
        kf0 = kn0; kf1 = kn1;
    }

    const float linv = 1.0f / l_acc;
    const int ig = i0 + 32 * w + l31;
    #pragma unroll
    for (int ct = 0; ct < 4; ++ct) {
        #pragma unroll
        for (int r = 0; r < 16; ++r) {
            int c = 32 * ct + (r & 3) + 8 * (r >> 2) + 4 * H;
            Og[(size_t)c * NPIX + ig] = __float2bfloat16(acc[ct][r] * linv);
        }
    }
}

// ---------------------------------------------------------------------------
extern "C" void kernel_launch(void* const* d_in, const int* in_sizes, int n_in,
                              void* d_out, int out_size, void* d_ws, size_t ws_size,
                              hipStream_t stream)
{
    (void)in_sizes; (void)n_in; (void)out_size; (void)ws_size;
    const float* h_t    = (const float*)d_in[0];
    const float* m_prev = (const float*)d_in[1];
    const float* wq_h   = (const float*)d_in[2];
    const float* wk_h   = (const float*)d_in[3];
    const float* wv_h   = (const float*)d_in[4];
    const float* wk_m   = (const float*)d_in[5];
    const float* wv_m   = (const float*)d_in[6];
    const float* wz_w   = (const float*)d_in[7];
    const float* wz_b   = (const float*)d_in[8];
    const float* wmi_dw = (const float*)d_in[9];
    const float* wmi_pw = (const float*)d_in[10];
    const float* whi_dw = (const float*)d_in[11];
    const float* whi_pw = (const float*)d_in[12];
    const float* bi     = (const float*)d_in[13];
    const float* wmg_dw = (const float*)d_in[14];
    const float* wmg_pw = (const float*)d_in[15];
    const float* whg_dw = (const float*)d_in[16];
    const float* whg_pw = (const float*)d_in[17];
    const float* bg     = (const float*)d_in[18];
    const float* wmo_dw = (const float*)d_in[19];
    const float* wmo_pw = (const float*)d_in[20];
    const float* who_dw = (const float*)d_in[21];
    const float* who_pw = (const float*)d_in[22];
    const float* bo     = (const float*)d_in[23];
    const float* wf_w   = (const float*)d_in[24];
    const float* wf_b   = (const float*)d_in[25];

    float* out = (float*)d_out;               // [h_out | m_t]

    const size_t SQE = (size_t)BB * NPIX * CRED;   // 524288 elems
    const size_t SV  = (size_t)BB * CCH * NPIX;    // 4194304 elems

    __hip_bfloat16* Wb  = (__hip_bfloat16*)d_ws;   // 11*16384 bf16
    __hip_bfloat16* Qt  = Wb + 184320;
    __hip_bfloat16* Kht = Qt  + SQE;
    __hip_bfloat16* Kmt = Kht + SQE;
    __hip_bfloat16* Vhb = Kmt + SQE;
    __hip_bfloat16* Vmb = Vhb + SV;
    __hip_bfloat16* Zhb = Vmb + SV;
    __hip_bfloat16* Zmb = Zhb + SV;
    __hip_bfloat16* Dd  = Zmb + SV;                // 6 x SV bf16 (dw outputs)
    float* Ev = (float*)(Dd + 6 * SV);             // Z (f32)

    dim3 blk(256);
    dim3 pwg(NPIX / 64, BB);

    // weight conversion (bf16 slots)
    wcvt_kernel<<<dim3(16, 11), blk, 0, stream>>>(
        Wb, wv_h, wv_m, wz_w, wmi_pw, whi_pw, wmg_pw, whg_pw, wmo_pw, who_pw, wf_w);

    // Q/K projections (transposed bf16) + V projections (bf16, MFMA)
    qkproj_kernel<<<dim3(NPIX / 128, BB, 3), blk, 0, stream>>>(
        Qt, Kht, Kmt, h_t, m_prev, wq_h, wk_h, wk_m);
    pw_mfma<false, false, true><<<pwg, blk, 0, stream>>>(
        Vhb, h_t, Wb + 0 * 16384, nullptr, nullptr, nullptr, nullptr);
    pw_mfma<false, false, true><<<pwg, blk, 0, stream>>>(
        Vmb, m_prev, Wb + 1 * 16384, nullptr, nullptr, nullptr, nullptr);

    // dual attention (MFMA) -> Zh, Zm (bf16)
    attn_mfma_kernel<<<dim3(NPIX / 128, BB, 2), blk, 0, stream>>>(
        Zhb, Zmb, Qt, Kht, Kmt, Vhb, Vmb);

    // Z = wz * [Zh; Zm] + wz_b -> Ev (f32)
    pw_mfma<true, true, false><<<pwg, blk, 0, stream>>>(
        Ev, Zhb, Wb + 2 * 16384, Zmb, Wb + 3 * 16384, wz_b, nullptr);

    // all six depthwise convs -> Dd[0..5] (bf16, [b][y][c][x] layout)
    dw6_kernel<<<dim3(CCH, BB, 2), blk, 0, stream>>>(
        Dd, SV, Ev, h_t, wmi_dw, wmg_dw, wmo_dw, whi_dw, whg_dw, who_dw);

    // fused gates + combine + final GEMM: m_t -> out+SV, h_out -> out
    gates3_kernel<<<dim3(32, BB), blk, 0, stream>>>(
        out + SV, out, Dd, SV, Wb + 4 * 16384, Wb + 10 * 16384,
        bi, bg, bo, wf_b, m_prev, h_t);
}

// Round 11
// 281.560 us; speedup vs baseline: 3.4422x; 1.0247x over previous
//
#include <hip/hip_runtime.h>
#include <hip/hip_bf16.h>
#include <math.h>

#define BB   32
#define CCH  128
#define NPIX 1024
#define CRED 16

typedef __attribute__((ext_vector_type(8)))  short short8;
typedef __attribute__((ext_vector_type(16))) float f32x16;

union Frag8 { short8 s8; unsigned u[4]; };

__device__ __forceinline__ unsigned pack2bf(float lo, float hi) {
    union { __hip_bfloat16 h; unsigned short u; } a, b;
    a.h = __float2bfloat16(lo);
    b.h = __float2bfloat16(hi);
    return (unsigned)a.u | ((unsigned)b.u << 16);
}

// ---------------------------------------------------------------------------
// Weight pre-conversion: 11 slots of [128][128] bf16.
// slots: 0 wv_h, 1 wv_m, 2 wz[:, :128], 3 wz[:, 128:], 4 wmi_pw, 5 whi_pw,
//        6 wmg_pw, 7 whg_pw, 8 wmo_pw, 9 who_pw, 10 wf_w
// ---------------------------------------------------------------------------
__global__ __launch_bounds__(256)
void wcvt_kernel(__hip_bfloat16* __restrict__ dst,
                 const float* __restrict__ s0, const float* __restrict__ s1,
                 const float* __restrict__ wz,
                 const float* __restrict__ s4, const float* __restrict__ s5,
                 const float* __restrict__ s6, const float* __restrict__ s7,
                 const float* __restrict__ s8, const float* __restrict__ s9,
                 const float* __restrict__ s10)
{
    const int slot = blockIdx.y;
    const int e = (blockIdx.x * 256 + threadIdx.x) * 4;
    const float* src;
    size_t soff;
    if (slot == 2 || slot == 3) {
        const int o = e >> 7, c = e & 127;
        src = wz;
        soff = (size_t)o * 256 + (slot == 3 ? 128 : 0) + c;
    } else {
        switch (slot) {
            case 0: src = s0; break;  case 1: src = s1; break;
            case 4: src = s4; break;  case 5: src = s5; break;
            case 6: src = s6; break;  case 7: src = s7; break;
            case 8: src = s8; break;  case 9: src = s9; break;
            default: src = s10; break;
        }
        soff = e;
    }
    float4 v = *(const float4*)&src[soff];
    uint2 pk = make_uint2(pack2bf(v.x, v.y), pack2bf(v.z, v.w));
    *(uint2*)&dst[(size_t)slot * 16384 + e] = pk;
}

// ---------------------------------------------------------------------------
// LDS staging for 64px MFMA GEMMs: tile [64 px][128 ch] bf16, 8B-granule XOR
// swizzle (granule g at byte p*256 + ((g ^ (p&31))<<3)).
// ---------------------------------------------------------------------------
__device__ __forceinline__ void stage_tile(char* buf, const float* Xb, int tid)
{
    const int p  = tid & 63;
    const int gb = tid >> 6;
    float xr[32];
    #pragma unroll
    for (int u = 0; u < 8; ++u) {
        const int c0 = (u * 4 + gb) * 4;
        #pragma unroll
        for (int j = 0; j < 4; ++j)
            xr[u * 4 + j] = Xb[(size_t)(c0 + j) * NPIX + p];
    }
    #pragma unroll
    for (int u = 0; u < 8; ++u) {
        const int g = u * 4 + gb;
        uint2 pk = make_uint2(pack2bf(xr[u * 4 + 0], xr[u * 4 + 1]),
                              pack2bf(xr[u * 4 + 2], xr[u * 4 + 3]));
        *(uint2*)(buf + p * 256 + ((g ^ (p & 31)) << 3)) = pk;
    }
}

__device__ __forceinline__ void stage_tile_bf16(char* buf,
                                                const __hip_bfloat16* Xb, int tid)
{
    const unsigned short* Xu = (const unsigned short*)Xb;
    const int p  = tid & 63;
    const int gb = tid >> 6;
    #pragma unroll
    for (int u = 0; u < 8; ++u) {
        const int g  = u * 4 + gb;
        const int c0 = g * 4;
        unsigned e0 = Xu[(size_t)(c0 + 0) * NPIX + p];
        unsigned e1 = Xu[(size_t)(c0 + 1) * NPIX + p];
        unsigned e2 = Xu[(size_t)(c0 + 2) * NPIX + p];
        unsigned e3 = Xu[(size_t)(c0 + 3) * NPIX + p];
        uint2 pk = make_uint2(e0 | (e1 << 16), e2 | (e3 << 16));
        *(uint2*)(buf + p * 256 + ((g ^ (p & 31)) << 3)) = pk;
    }
}

__device__ __forceinline__ void compute_pass(const char* buf,
                                             const __hip_bfloat16* W,
                                             f32x16* acc,
                                             int l31, int H, int ntw, int mth)
{
    const int prow = (32 * ntw + l31) * 256;
    #pragma unroll
    for (int kt = 0; kt < 8; ++kt) {
        Frag8 bf_;
        const int g0 = 4 * kt + 2 * H;
        *(uint2*)&bf_.u[0] = *(const uint2*)(buf + prow + (((g0    ) ^ l31) << 3));
        *(uint2*)&bf_.u[2] = *(const uint2*)(buf + prow + (((g0 + 1) ^ l31) << 3));
        #pragma unroll
        for (int mi = 0; mi < 2; ++mi) {
            const int m = 32 * (2 * mth + mi) + l31;
            short8 af = *(const short8*)&W[(size_t)m * 128 + 16 * kt + 8 * H];
            acc[mi] = __builtin_amdgcn_mfma_f32_32x32x16_bf16(af, bf_.s8, acc[mi], 0, 0, 0);
        }
    }
}

// ---------------------------------------------------------------------------
// MFMA pointwise GEMM (64px tiles). out[b][o][p] = sum_c W1[o][c]X1[b][c][p]
// (+W2·X2) (+bias) (+res).
// ---------------------------------------------------------------------------
template<bool TWO, bool BF16IN, bool BF16OUT>
__global__ __launch_bounds__(256)
void pw_mfma(void* __restrict__ outv,
             const void* __restrict__ X1, const __hip_bfloat16* __restrict__ W1,
             const void* __restrict__ X2, const __hip_bfloat16* __restrict__ W2,
             const float* __restrict__ bias, const float* __restrict__ res)
{
    __shared__ __align__(16) char Xs[2][16384];
    const int tid = threadIdx.x;
    const int b   = blockIdx.y;
    const int p0  = blockIdx.x * 64;
    const int l31 = tid & 31;
    const int H   = (tid & 63) >> 5;
    const int w   = tid >> 6;
    const int ntw = w & 1;
    const int mth = w >> 1;
    const size_t boff = (size_t)b * CCH * NPIX + p0;

    if (BF16IN) stage_tile_bf16(&Xs[0][0], (const __hip_bfloat16*)X1 + boff, tid);
    else        stage_tile     (&Xs[0][0], (const float*)X1 + boff, tid);
    if (TWO) {
        if (BF16IN) stage_tile_bf16(&Xs[1][0], (const __hip_bfloat16*)X2 + boff, tid);
        else        stage_tile     (&Xs[1][0], (const float*)X2 + boff, tid);
    }
    __syncthreads();

    f32x16 acc[2];
    #pragma unroll
    for (int mi = 0; mi < 2; ++mi)
        #pragma unroll
        for (int e = 0; e < 16; ++e) acc[mi][e] = 0.f;

    compute_pass(&Xs[0][0], W1, acc, l31, H, ntw, mth);
    if (TWO)
        compute_pass(&Xs[1][0], W2, acc, l31, H, ntw, mth);

    const int pg = p0 + 32 * ntw + l31;
    #pragma unroll
    for (int mi = 0; mi < 2; ++mi) {
        const int mtile = 2 * mth + mi;
        #pragma unroll
        for (int r = 0; r < 16; ++r) {
            const int m = 32 * mtile + (r & 3) + 8 * (r >> 2) + 4 * H;
            float v = acc[mi][r];
            if (bias) v += bias[m];
            const size_t off = ((size_t)b * CCH + m) * NPIX + pg;
            if (res) v += res[off];
            if (BF16OUT) ((__hip_bfloat16*)outv)[off] = __float2bfloat16(v);
            else         ((float*)outv)[off] = v;
        }
    }
}

// ---------------------------------------------------------------------------
// Q/K projection -> transposed bf16 [B][NPIX][16]. z: 0=Q(h), 1=Kh(h), 2=Km(m)
// ---------------------------------------------------------------------------
__global__ __launch_bounds__(256)
void qkproj_kernel(__hip_bfloat16* __restrict__ Qt,
                   __hip_bfloat16* __restrict__ Kht,
                   __hip_bfloat16* __restrict__ Kmt,
                   const float* __restrict__ h_t,
                   const float* __restrict__ m_prev,
                   const float* __restrict__ wq,
                   const float* __restrict__ wkh,
                   const float* __restrict__ wkm)
{
    const int b  = blockIdx.y;
    const int p0 = blockIdx.x * 128;
    const float* X; const float* W; __hip_bfloat16* Out;
    if (blockIdx.z == 0)      { X = h_t;    W = wq;  Out = Qt;  }
    else if (blockIdx.z == 1) { X = h_t;    W = wkh; Out = Kht; }
    else                      { X = m_prev; W = wkm; Out = Kmt; }

    __shared__ float Ws[16][128];
    __shared__ float Xs[32][132];
    const int tid = threadIdx.x;
    for (int i = tid; i < 16 * 128; i += 256)
        Ws[i / 128][i % 128] = W[i];

    const float* Xb = X + (size_t)b * CCH * NPIX;
    const int pl = tid & 127;
    const int h8 = tid >> 7;

    float acc[8];
    #pragma unroll
    for (int e = 0; e < 8; ++e) acc[e] = 0.f;

    for (int c0 = 0; c0 < CCH; c0 += 32) {
        __syncthreads();
        for (int idx = tid; idx < 32 * 32; idx += 256) {
            int r = idx >> 5, cp = (idx & 31) << 2;
            *(float4*)&Xs[r][cp] =
                *(const float4*)&Xb[(size_t)(c0 + r) * NPIX + p0 + cp];
        }
        __syncthreads();
        #pragma unroll 8
        for (int cc = 0; cc < 32; ++cc) {
            float xv = Xs[cc][pl];
            #pragma unroll
            for (int e = 0; e < 8; ++e)
                acc[e] += Ws[h8 * 8 + e][c0 + cc] * xv;
        }
    }

    Frag8 f;
    #pragma unroll
    for (int w = 0; w < 4; ++w)
        f.u[w] = pack2bf(acc[2 * w], acc[2 * w + 1]);
    *(short8*)&Out[((size_t)b * NPIX + p0 + pl) * 16 + 8 * h8] = f.s8;
}

// ---------------------------------------------------------------------------
// All six depthwise 3x3 convs in one dispatch. grid (C, B, 2).
// Output layout: D[s][b][y][c][x] (tile-contiguous bf16).
// ---------------------------------------------------------------------------
__global__ __launch_bounds__(256)
void dw6_kernel(__hip_bfloat16* __restrict__ D, size_t SVe,
                const float* __restrict__ Z, const float* __restrict__ h_t,
                const float* __restrict__ wmi, const float* __restrict__ wmg,
                const float* __restrict__ wmo,
                const float* __restrict__ whi, const float* __restrict__ whg,
                const float* __restrict__ who)
{
    const int c = blockIdx.x, b = blockIdx.y;
    const float* src; const float *kaw, *kbw, *kcw;
    __hip_bfloat16* dbase;
    if (blockIdx.z == 0) { src = Z;   kaw = wmi; kbw = wmg; kcw = wmo; dbase = D; }
    else                 { src = h_t; kaw = whi; kbw = whg; kcw = who; dbase = D + 3 * SVe; }
    src += ((size_t)b * CCH + c) * NPIX;

    float ka[9], kb[9], kc[9];
    #pragma unroll
    for (int j = 0; j < 9; ++j) {
        ka[j] = kaw[c * 9 + j];
        kb[j] = kbw[c * 9 + j];
        kc[j] = kcw[c * 9 + j];
    }

    __shared__ float t[34][36];
    const int tid = threadIdx.x;
    for (int idx = tid; idx < 34 * 34; idx += 256) {
        int y = idx / 34, x = idx % 34;
        int gy = y - 1, gx = x - 1;
        t[y][x] = (gy >= 0 && gy < 32 && gx >= 0 && gx < 32)
                      ? src[gy * 32 + gx] : 0.f;
    }
    __syncthreads();
    const int x = tid % 32, y0 = tid / 32;
    #pragma unroll
    for (int q = 0; q < 4; ++q) {
        int y = y0 + 8 * q;
        float s0 = 0.f, s1 = 0.f, s2 = 0.f;
        #pragma unroll
        for (int dy = 0; dy < 3; ++dy)
            #pragma unroll
            for (int dx = 0; dx < 3; ++dx) {
                float tv = t[y + dy][x + dx];
                s0 += tv * ka[dy * 3 + dx];
                s1 += tv * kb[dy * 3 + dx];
                s2 += tv * kc[dy * 3 + dx];
            }
        // [b][y][c][x] layout
        const size_t o = ((size_t)(b * 32 + y) * CCH + c) * 32 + x;
        dbase[o]           = __float2bfloat16(s0);
        dbase[SVe + o]     = __float2bfloat16(s1);
        dbase[2 * SVe + o] = __float2bfloat16(s2);
    }
}

// ---------------------------------------------------------------------------
// gates3 v2: fused gate GEMMs + LSTM combine + final GEMM.
// Block: 256 thr / 4 waves; (b, image-row y) = 32 px, 128 out-ch.
// 2x8KB ping-pong LDS; tiles loaded to REGISTERS 2 deep ahead (latency hidden
// under pass32); scatter = 4x b64 granule writes (in-register 4x4 bf16
// transpose) instead of 96x b16. 16 KB LDS, ~7 barriers.
// ---------------------------------------------------------------------------
struct TileRegs { uint2 v[4]; };

__device__ __forceinline__ void tload(TileRegs& t, const __hip_bfloat16* Dt,
                                      int cq, int pq)
{
    const unsigned short* src = (const unsigned short*)Dt;
    #pragma unroll
    for (int j = 0; j < 4; ++j)
        t.v[j] = *(const uint2*)(src + (4 * cq + j) * 32 + 4 * pq);
}

__device__ __forceinline__ unsigned half16(uint2 v, int i)
{
    unsigned w = (i < 2) ? v.x : v.y;
    return (w >> ((i & 1) * 16)) & 0xFFFFu;
}

__device__ __forceinline__ void tscat(char* buf, const TileRegs& t,
                                      int cq, int pq)
{
    #pragma unroll
    for (int i = 0; i < 4; ++i) {
        const int px = 4 * pq + i;
        unsigned e0 = half16(t.v[0], i), e1 = half16(t.v[1], i);
        unsigned e2 = half16(t.v[2], i), e3 = half16(t.v[3], i);
        uint2 pk = make_uint2(e0 | (e1 << 16), e2 | (e3 << 16));
        *(uint2*)(buf + px * 256 + ((cq ^ px) << 3)) = pk;
    }
}

__device__ __forceinline__ void pass32(const char* buf,
                                       const __hip_bfloat16* W,
                                       f32x16* acc, int l31, int H, int wv)
{
    const int prow = l31 * 256;
    #pragma unroll
    for (int kt = 0; kt < 8; ++kt) {
        Frag8 bf_;
        const int g0 = 4 * kt + 2 * H;
        *(uint2*)&bf_.u[0] = *(const uint2*)(buf + prow + (((g0    ) ^ l31) << 3));
        *(uint2*)&bf_.u[2] = *(const uint2*)(buf + prow + (((g0 + 1) ^ l31) << 3));
        const int m = 32 * wv + l31;
        short8 af = *(const short8*)&W[(size_t)m * 128 + 16 * kt + 8 * H];
        *acc = __builtin_amdgcn_mfma_f32_32x32x16_bf16(af, bf_.s8, *acc, 0, 0, 0);
    }
}

__global__ __launch_bounds__(256)
void gates3_kernel(float* __restrict__ mt_out, float* __restrict__ hout,
                   const __hip_bfloat16* __restrict__ D, size_t SVe,
                   const __hip_bfloat16* __restrict__ Wg,      // slots 4..9
                   const __hip_bfloat16* __restrict__ Wf,      // slot 10
                   const float* __restrict__ bi, const float* __restrict__ bg,
                   const float* __restrict__ bo, const float* __restrict__ wfb,
                   const float* __restrict__ mp, const float* __restrict__ h_t)
{
    __shared__ __align__(16) char Xs0[8192];
    __shared__ __align__(16) char Xs1[8192];
    const int tid = threadIdx.x;
    const int y   = blockIdx.x;
    const int b   = blockIdx.y;
    const int l31 = tid & 31;
    const int H   = (tid & 63) >> 5;
    const int wv  = tid >> 6;
    const int cq  = tid >> 3;        // 0..31 c-quad
    const int pq  = tid & 7;         // 0..7  px-quad
    const size_t tbase = (size_t)(b * 32 + y) * 4096;

    // tile order: {D0,D3, D1,D4, D2,D5} (Z-gate, h-gate pairs)
    const __hip_bfloat16* T0 = D + 0 * SVe + tbase;
    const __hip_bfloat16* T1 = D + 3 * SVe + tbase;
    const __hip_bfloat16* T2 = D + 1 * SVe + tbase;
    const __hip_bfloat16* T3 = D + 4 * SVe + tbase;
    const __hip_bfloat16* T4 = D + 2 * SVe + tbase;
    const __hip_bfloat16* T5 = D + 5 * SVe + tbase;

    f32x16 aI, aG, aO;
    #pragma unroll
    for (int e = 0; e < 16; ++e) { aI[e] = 0.f; aG[e] = 0.f; aO[e] = 0.f; }

    TileRegs rva, rvb;
    tload(rva, T0, cq, pq);
    tload(rvb, T1, cq, pq);

    tscat(Xs0, rva, cq, pq);                 // tile0
    tload(rva, T2, cq, pq);                  // prefetch tile2
    __syncthreads();                         // b1
    tscat(Xs1, rvb, cq, pq);                 // tile1
    tload(rvb, T3, cq, pq);                  // prefetch tile3
    pass32(Xs0, Wg + 0 * 16384, &aI, l31, H, wv);   // tile0
    __syncthreads();                         // b2
    tscat(Xs0, rva, cq, pq);                 // tile2
    tload(rva, T4, cq, pq);                  // prefetch tile4
    pass32(Xs1, Wg + 1 * 16384, &aI, l31, H, wv);   // tile1
    __syncthreads();                         // b3
    tscat(Xs1, rvb, cq, pq);                 // tile3
    tload(rvb, T5, cq, pq);                  // prefetch tile5
    pass32(Xs0, Wg + 2 * 16384, &aG, l31, H, wv);   // tile2
    __syncthreads();                         // b4
    tscat(Xs0, rva, cq, pq);                 // tile4
    pass32(Xs1, Wg + 3 * 16384, &aG, l31, H, wv);   // tile3
    __syncthreads();                         // b5
    tscat(Xs1, rvb, cq, pq);                 // tile5
    pass32(Xs0, Wg + 4 * 16384, &aO, l31, H, wv);   // tile4
    __syncthreads();                         // b6
    pass32(Xs1, Wg + 5 * 16384, &aO, l31, H, wv);   // tile5

    // ---- combine (mp loaded here, coalesced) ----
    const int pg = (y << 5) + l31;
    float om[16];
    #pragma unroll
    for (int r = 0; r < 16; ++r) {
        const int m = 32 * wv + (r & 3) + 8 * (r >> 2) + 4 * H;
        const size_t off = ((size_t)b * CCH + m) * NPIX + pg;
        float it = 1.f / (1.f + __expf(-(aI[r] + bi[m])));
        float gt = tanhf(aG[r] + bg[m]);
        float ot = 1.f / (1.f + __expf(-(aO[r] + bo[m])));
        float mt = (1.f - it) * mp[off] + it * gt;
        mt_out[off] = mt;
        om[r] = ot * mt;
    }

    // h_t prefetch for epilogue
    float htv[16];
    #pragma unroll
    for (int r = 0; r < 16; ++r) {
        const int m = 32 * wv + (r & 3) + 8 * (r >> 2) + 4 * H;
        htv[r] = h_t[((size_t)b * CCH + m) * NPIX + pg];
    }

    // restage om -> Xs0 (Xs0 free after b6; Xs1 still being read — disjoint)
    #pragma unroll
    for (int q = 0; q < 4; ++q) {
        const int g = 8 * wv + 2 * q + H;
        uint2 pk = make_uint2(pack2bf(om[4 * q + 0], om[4 * q + 1]),
                              pack2bf(om[4 * q + 2], om[4 * q + 3]));
        *(uint2*)(Xs0 + l31 * 256 + ((g ^ l31) << 3)) = pk;
    }
    __syncthreads();                         // b7

    f32x16 aF;
    #pragma unroll
    for (int e = 0; e < 16; ++e) aF[e] = 0.f;
    pass32(Xs0, Wf, &aF, l31, H, wv);

    #pragma unroll
    for (int r = 0; r < 16; ++r) {
        const int m = 32 * wv + (r & 3) + 8 * (r >> 2) + 4 * H;
        const size_t off = ((size_t)b * CCH + m) * NPIX + pg;
        hout[off] = aF[r] + wfb[m] + htv[r];
    }
}

// ---------------------------------------------------------------------------
// MFMA dual-stream attention (bf16 Z output).
// ---------------------------------------------------------------------------
__global__ __launch_bounds__(256)
void attn_mfma_kernel(__hip_bfloat16* __restrict__ Zh,
                      __hip_bfloat16* __restrict__ Zm,
                      const __hip_bfloat16* __restrict__ Qt,
                      const __hip_bfloat16* __restrict__ Kht,
                      const __hip_bfloat16* __restrict__ Kmt,
                      const __hip_bfloat16* __restrict__ Vh,
                      const __hip_bfloat16* __restrict__ Vm)
{
    const int b  = blockIdx.y;
    const int i0 = blockIdx.x * 128;
    const __hip_bfloat16* Kt; const __hip_bfloat16* Vg; __hip_bfloat16* Og;
    if (blockIdx.z == 0) { Kt = Kht; Vg = Vh; Og = Zh; }
    else                 { Kt = Kmt; Vg = Vm; Og = Zm; }
    Kt += (size_t)b * NPIX * 16;
    Vg += (size_t)b * CCH * NPIX;
    Og += (size_t)b * CCH * NPIX;

    __shared__ __align__(16) char Vs[2][128 * 64 * 2];

    const int tid = threadIdx.x;
    const int w   = tid >> 6;
    const int l   = tid & 63;
    const int l31 = l & 31;
    const int H   = l >> 5;

    const __hip_bfloat16* Qb = Qt + (size_t)b * NPIX * 16;
    short8 qf = *(const short8*)&Qb[((size_t)(i0 + 32 * w + l31)) * 16 + 8 * H];

    f32x16 acc[4];
    #pragma unroll
    for (int ct = 0; ct < 4; ++ct)
        #pragma unroll
        for (int e = 0; e < 16; ++e) acc[ct][e] = 0.f;
    float l_acc = 0.f;

    int cu[4], ldsoff[4]; size_t goff[4];
    #pragma unroll
    for (int u = 0; u < 4; ++u) {
        int idx = tid + 256 * u;
        cu[u] = idx >> 3;
        int jg = idx & 7;
        ldsoff[u] = cu[u] * 128 + ((jg ^ (cu[u] & 7)) << 4);
        goff[u]   = (size_t)cu[u] * NPIX + 8 * jg;
    }
    const int slotx_base = (l31 & 7);

    short8 v0 = *(const short8*)&Vg[goff[0]];
    short8 v1 = *(const short8*)&Vg[goff[1]];
    short8 v2 = *(const short8*)&Vg[goff[2]];
    short8 v3 = *(const short8*)&Vg[goff[3]];
    short8 kf0 = *(const short8*)&Kt[(size_t)(0 + l31) * 16 + 8 * H];
    short8 kf1 = *(const short8*)&Kt[(size_t)(32 + l31) * 16 + 8 * H];

    for (int t = 0; t < 16; ++t) {
        char* buf = &Vs[t & 1][0];
        *(short8*)(buf + ldsoff[0]) = v0;
        *(short8*)(buf + ldsoff[1]) = v1;
        *(short8*)(buf + ldsoff[2]) = v2;
        *(short8*)(buf + ldsoff[3]) = v3;

        short8 kn0 = kf0, kn1 = kf1;
        if (t < 15) {
            const int jn = (t + 1) * 64;
            v0 = *(const short8*)&Vg[goff[0] + jn];
            v1 = *(const short8*)&Vg[goff[1] + jn];
            v2 = *(const short8*)&Vg[goff[2] + jn];
            v3 = *(const short8*)&Vg[goff[3] + jn];
            kn0 = *(const short8*)&Kt[(size_t)(jn + l31) * 16 + 8 * H];
            kn1 = *(const short8*)&Kt[(size_t)(jn + 32 + l31) * 16 + 8 * H];
        }
        __syncthreads();

        #pragma unroll
        for (int jt = 0; jt < 2; ++jt) {
            short8 kcur = (jt == 0) ? kf0 : kf1;
            f32x16 z;
            #pragma unroll
            for (int e = 0; e < 16; ++e) z[e] = 0.f;
            f32x16 s = __builtin_amdgcn_mfma_f32_32x32x16_bf16(kcur, qf, z, 0, 0, 0);

            float p[16];
            float ls = 0.f;
            #pragma unroll
            for (int r = 0; r < 16; ++r) { p[r] = __expf(s[r]); ls += p[r]; }
            l_acc += ls + __shfl_xor(ls, 32);

            unsigned w0[4], w1[4], x0[4], x1[4];
            #pragma unroll
            for (int g = 0; g < 4; ++g) {
                w0[g] = pack2bf(p[4 * g + 0], p[4 * g + 1]);
                w1[g] = pack2bf(p[4 * g + 2], p[4 * g + 3]);
            }
            #pragma unroll
            for (int g = 0; g < 4; ++g) {
                x0[g] = __shfl_xor(w0[g], 32);
                x1[g] = __shfl_xor(w1[g], 32);
            }
            #pragma unroll
            for (int js = 0; js < 2; ++js) {
                const int gA = 2 * js, gB = 2 * js + 1;
                Frag8 pb;
                pb.u[0] = H ? x0[gB] : w0[gA];
                pb.u[1] = H ? x1[gB] : w1[gA];
                pb.u[2] = H ? w0[gB] : x0[gA];
                pb.u[3] = H ? w1[gB] : x1[gA];
                const int slot = 4 * jt + 2 * js + H;
                const int sx   = (slot ^ slotx_base) << 4;
                #pragma unroll
                for (int ct = 0; ct < 4; ++ct) {
                    short8 vf = *(short8*)(buf + (32 * ct + l31) * 128 + sx);
                    acc[ct] = __builtin_amdgcn_mfma_f32_32x32x16_bf16(
                        vf, pb.s8, acc[ct], 0, 0, 0);
                }
            }
        }
        kf0 = kn0; kf1 = kn1;
    }

    const float linv = 1.0f / l_acc;
    const int ig = i0 + 32 * w + l31;
    #pragma unroll
    for (int ct = 0; ct < 4; ++ct) {
        #pragma unroll
        for (int r = 0; r < 16; ++r) {
            int c = 32 * ct + (r & 3) + 8 * (r >> 2) + 4 * H;
            Og[(size_t)c * NPIX + ig] = __float2bfloat16(acc[ct][r] * linv);
        }
    }
}

// ---------------------------------------------------------------------------
extern "C" void kernel_launch(void* const* d_in, const int* in_sizes, int n_in,
                              void* d_out, int out_size, void* d_ws, size_t ws_size,
                              hipStream_t stream)
{
    (void)in_sizes; (void)n_in; (void)out_size; (void)ws_size;
    const float* h_t    = (const float*)d_in[0];
    const float* m_prev = (const float*)d_in[1];
    const float* wq_h   = (const float*)d_in[2];
    const float* wk_h   = (const float*)d_in[3];
    const float* wv_h   = (const float*)d_in[4];
    const float* wk_m   = (const float*)d_in[5];
    const float* wv_m   = (const float*)d_in[6];
    const float* wz_w   = (const float*)d_in[7];
    const float* wz_b   = (const float*)d_in[8];
    const float* wmi_dw = (const float*)d_in[9];
    const float* wmi_pw = (const float*)d_in[10];
    const float* whi_dw = (const float*)d_in[11];
    const float* whi_pw = (const float*)d_in[12];
    const float* bi     = (const float*)d_in[13];
    const float* wmg_dw = (const float*)d_in[14];
    const float* wmg_pw = (const float*)d_in[15];
    const float* whg_dw = (const float*)d_in[16];
    const float* whg_pw = (const float*)d_in[17];
    const float* bg     = (const float*)d_in[18];
    const float* wmo_dw = (const float*)d_in[19];
    const float* wmo_pw = (const float*)d_in[20];
    const float* who_dw = (const float*)d_in[21];
    const float* who_pw = (const float*)d_in[22];
    const float* bo     = (const float*)d_in[23];
    const float* wf_w   = (const float*)d_in[24];
    const float* wf_b   = (const float*)d_in[25];

    float* out = (float*)d_out;               // [h_out | m_t]

    const size_t SQE = (size_t)BB * NPIX * CRED;   // 524288 elems
    const size_t SV  = (size_t)BB * CCH * NPIX;    // 4194304 elems

    __hip_bfloat16* Wb  = (__hip_bfloat16*)d_ws;   // 11*16384 bf16
    __hip_bfloat16* Qt  = Wb + 184320;
    __hip_bfloat16* Kht = Qt  + SQE;
    __hip_bfloat16* Kmt = Kht + SQE;
    __hip_bfloat16* Vhb = Kmt + SQE;
    __hip_bfloat16* Vmb = Vhb + SV;
    __hip_bfloat16* Zhb = Vmb + SV;
    __hip_bfloat16* Zmb = Zhb + SV;
    __hip_bfloat16* Dd  = Zmb + SV;                // 6 x SV bf16 (dw outputs)
    float* Ev = (float*)(Dd + 6 * SV);             // Z (f32)

    dim3 blk(256);
    dim3 pwg(NPIX / 64, BB);

    // weight conversion (bf16 slots)
    wcvt_kernel<<<dim3(16, 11), blk, 0, stream>>>(
        Wb, wv_h, wv_m, wz_w, wmi_pw, whi_pw, wmg_pw, whg_pw, wmo_pw, who_pw, wf_w);

    // Q/K projections (transposed bf16) + V projections (bf16, MFMA)
    qkproj_kernel<<<dim3(NPIX / 128, BB, 3), blk, 0, stream>>>(
        Qt, Kht, Kmt, h_t, m_prev, wq_h, wk_h, wk_m);
    pw_mfma<false, false, true><<<pwg, blk, 0, stream>>>(
        Vhb, h_t, Wb + 0 * 16384, nullptr, nullptr, nullptr, nullptr);
    pw_mfma<false, false, true><<<pwg, blk, 0, stream>>>(
        Vmb, m_prev, Wb + 1 * 16384, nullptr, nullptr, nullptr, nullptr);

    // dual attention (MFMA) -> Zh, Zm (bf16)
    attn_mfma_kernel<<<dim3(NPIX / 128, BB, 2), blk, 0, stream>>>(
        Zhb, Zmb, Qt, Kht, Kmt, Vhb, Vmb);

    // Z = wz * [Zh; Zm] + wz_b -> Ev (f32)
    pw_mfma<true, true, false><<<pwg, blk, 0, stream>>>(
        Ev, Zhb, Wb + 2 * 16384, Zmb, Wb + 3 * 16384, wz_b, nullptr);

    // all six depthwise convs -> Dd[0..5] (bf16, [b][y][c][x] layout)
    dw6_kernel<<<dim3(CCH, BB, 2), blk, 0, stream>>>(
        Dd, SV, Ev, h_t, wmi_dw, wmg_dw, wmo_dw, whi_dw, whg_dw, who_dw);

    // fused gates + combine + final GEMM: m_t -> out+SV, h_out -> out
    gates3_kernel<<<dim3(32, BB), blk, 0, stream>>>(
        out + SV, out, Dd, SV, Wb + 4 * 16384, Wb + 10 * 16384,
        bi, bg, bo, wf_b, m_prev, h_t);
}